// Round 5
// baseline (171.564 us; speedup 1.0000x reference)
//
#include <hip/hip_runtime.h>
#include <hip/hip_bf16.h>

typedef unsigned int u32;
typedef unsigned short u16;
typedef unsigned long long u64;
typedef __attribute__((ext_vector_type(8))) short short8;
typedef __attribute__((ext_vector_type(4))) float f32x4;

#define BATCH 4
#define SEQ   4096
#define DIM   768
#define HD    64
#define NROW  (BATCH*SEQ)   // 16384
#define LOG2E 1.44269504088896f
#define SSCALE (0.125f * LOG2E)
#define CSHIFT (-32.0f)      // fixed exp2-domain shift (softmax shift-invariant)
#define NEGBIG (-1.0e30f)
#define VSTRIDE 4224         // vT row stride in u16 (breaks L2 channel camping)
#define PSLOTB 4224          // partial slot: 4096 B bf16 O[32][64] + 128 B f32 l[32]

__device__ __forceinline__ float ex2(float x) { return __builtin_amdgcn_exp2f(x); }
__device__ __forceinline__ float bfbits2f(u16 u) {
    return __uint_as_float(((u32)u) << 16);
}
__device__ __forceinline__ u16 f2bf(float f) {
    return (u16)((__float_as_uint(f) + 0x8000u) >> 16);
}
__device__ __forceinline__ u32 pkbf(float a, float b) { // lo16=bf(a), hi16=bf(b)
    u32 xa = __float_as_uint(a) + 0x8000u;
    u32 xb = __float_as_uint(b) + 0x8000u;
    return __builtin_amdgcn_perm(xb, xa, 0x07060302);
}
// Deterministic per-wave dtype sniff (same answer in every wave/block).
__device__ __forceinline__ int sniff_bf16(const u32* x) {
    u32 w = x[threadIdx.x & 63];
    u32 lo = w & 0xffffu;
    u32 e  = (lo >> 7) & 0xffu;
    bool ok = (lo == 0u) || (e >= 96u && e <= 134u);
    u64 bal = __ballot(ok);
    return (__popcll(bal) >= 48) ? 1 : 0;
}

// ---------------- W pre-conversion: fp32 -> bf16, ONCE ---------------------
// qkv formerly converted the full fp32 W per block (256x redundant: 37.7M
// packs + 147 MB fp32 L2 reads). Convert once to wb[192][768] bf16; qkv
// streams bf16 W directly. 72 blocks x 256 thr x 8 elems = 147456 = 192*768.
__global__ __launch_bounds__(256) void wconv_kernel(
    const u32* __restrict__ xs,
    const void* __restrict__ wq, const void* __restrict__ wk,
    const void* __restrict__ wv, u16* __restrict__ wb)
{
    const int flag = sniff_bf16(xs);
    const int j = blockIdx.x * 256 + threadIdx.x;   // 0..18431
    const int e = j * 8;
    const int r = e / DIM;          // 0..191  ([wq;wk;wv] stacked)
    const int c = e - r * DIM;
    const void* src = (r < 64) ? wq : (r < 128) ? wk : wv;
    const long soff = (long)(r & 63) * DIM + c;
    if (flag) {
        *reinterpret_cast<short8*>(wb + (long)r * DIM + c) =
            *reinterpret_cast<const short8*>((const u16*)src + soff);
    } else {
        const float* p = (const float*)src + soff;
        float4 a = *reinterpret_cast<const float4*>(p);
        float4 d = *reinterpret_cast<const float4*>(p + 4);
        union { u32 u[4]; short8 s; } un;
        un.u[0] = pkbf(a.x, a.y); un.u[1] = pkbf(a.z, a.w);
        un.u[2] = pkbf(d.x, d.y); un.u[3] = pkbf(d.z, d.w);
        *reinterpret_cast<short8*>(wb + (long)r * DIM + c) = un.s;
    }
}

// ---------------- QKV projection: LDS-tiled GEMM (m97 shape) ----------------
// Blocks 0..255: block tile = 64 rows x 192 cols, K staged 64-wide in LDS
// (X 8 KB + W 24 KB, chunk^(row&7) swizzle), register prefetch of next tile.
// W comes pre-converted (bf16) from wconv_kernel.
// Blocks 256..257: bit-pack padding mask via ballot.
__global__ __launch_bounds__(512, 4) void qkv_kernel(
    const void* __restrict__ x, const u16* __restrict__ wb,
    const int* __restrict__ mask,
    u16* __restrict__ qws, u16* __restrict__ kws, u16* __restrict__ vTws,
    u32* __restrict__ mb)
{
    const int t = threadIdx.x;
    const int l = t & 63;
    const int w = t >> 6;

    if (blockIdx.x >= 256) {            // ---- mask bit-pack ----
        const int base = (blockIdx.x - 256) * 8192 + w * 1024;
#pragma unroll
        for (int it = 0; it < 16; ++it) {
            const int idx = base + it * 64 + l;
            u64 bal = __ballot(mask[idx] != 0);
            if (l == 0)       mb[idx >> 5] = (u32)bal;
            else if (l == 32) mb[idx >> 5] = (u32)(bal >> 32);
        }
        return;
    }

    const int flag = sniff_bf16((const u32*)x);
    __shared__ __align__(16) u16 Xl[64 * 64];    // 8 KB,  slot r*64 + cc*8
    __shared__ __align__(16) u16 Wl[192 * 64];   // 24 KB, slot n*64 + cc*8
    __shared__ u16 Vt[64][66];                   // 8.4 KB transpose staging

    const int li = l & 15;
    const int g  = l >> 4;
    const int g4 = g * 4;
    const int strip = w & 3;            // 16-row strip
    const int nhalf = w >> 2;           // 96-col half
    const int m0 = blockIdx.x * 64;
    const int b  = m0 >> 12;

    auto ldbf = [&](const void* bp, long off) -> short8 {
        if (flag) return *reinterpret_cast<const short8*>((const u16*)bp + off);
        const float* p = (const float*)bp + off;
        float4 a = *reinterpret_cast<const float4*>(p);
        float4 c = *reinterpret_cast<const float4*>(p + 4);
        union { u32 u[4]; short8 s; } un;
        un.u[0] = pkbf(a.x, a.y); un.u[1] = pkbf(a.z, a.w);
        un.u[2] = pkbf(c.x, c.y); un.u[3] = pkbf(c.z, c.w);
        return un.s;
    };

    // ---- staging source mapping (kc-invariant parts) ----
    const int xr = t >> 3, xcc = t & 7, xc = xcc ^ (xr & 7);
    const long xsoff = (long)(m0 + xr) * DIM + xc * 8;
    long wboff[3]; int wdst[3];
#pragma unroll
    for (int j = 0; j < 3; ++j) {
        const int idx = j * 512 + t;
        const int r = idx >> 3, cc = idx & 7, c = cc ^ (r & 7);
        wboff[j] = (long)r * DIM + c * 8;     // r = 0..191 into stacked wb
        wdst[j]  = idx * 8;                   // u16 offset into Wl
    }

    // ---- fragment read offsets (kc-invariant, u16 units) ----
    const int am = strip * 16 + li;
    const int a0off = am * 64 + ((g       ^ (am & 7)) * 8);
    const int a1off = am * 64 + (((g | 4) ^ (am & 7)) * 8);
    int boff[12];
#pragma unroll
    for (int ns = 0; ns < 6; ++ns) {
        const int n = nhalf * 96 + ns * 16 + li;
        boff[2*ns]   = n * 64 + ((g       ^ (n & 7)) * 8);
        boff[2*ns+1] = n * 64 + (((g | 4) ^ (n & 7)) * 8);
    }

    f32x4 acc[6];
#pragma unroll
    for (int i = 0; i < 6; ++i) acc[i] = (f32x4){0.f, 0.f, 0.f, 0.f};

    short8 xs  = ldbf(x, xsoff);
    short8 ws0 = *reinterpret_cast<const short8*>(wb + wboff[0]);
    short8 ws1 = *reinterpret_cast<const short8*>(wb + wboff[1]);
    short8 ws2 = *reinterpret_cast<const short8*>(wb + wboff[2]);

    for (int kc = 0; kc < 12; ++kc) {
        __syncthreads();                 // previous K-step's LDS reads done
        *reinterpret_cast<short8*>(&Xl[t * 8])    = xs;
        *reinterpret_cast<short8*>(&Wl[wdst[0]])  = ws0;
        *reinterpret_cast<short8*>(&Wl[wdst[1]])  = ws1;
        *reinterpret_cast<short8*>(&Wl[wdst[2]])  = ws2;
        if (kc < 11) {                   // prefetch next staging tile
            const long o = (long)(kc + 1) * 64;
            xs  = ldbf(x, xsoff + o);
            ws0 = *reinterpret_cast<const short8*>(wb + wboff[0] + o);
            ws1 = *reinterpret_cast<const short8*>(wb + wboff[1] + o);
            ws2 = *reinterpret_cast<const short8*>(wb + wboff[2] + o);
        }
        __syncthreads();                 // staging visible
        short8 af0 = *reinterpret_cast<const short8*>(&Xl[a0off]);
        short8 af1 = *reinterpret_cast<const short8*>(&Xl[a1off]);
#pragma unroll
        for (int ns = 0; ns < 6; ++ns) {
            short8 b0 = *reinterpret_cast<const short8*>(&Wl[boff[2*ns]]);
            short8 b1 = *reinterpret_cast<const short8*>(&Wl[boff[2*ns+1]]);
            acc[ns] = __builtin_amdgcn_mfma_f32_16x16x32_bf16(af0, b0, acc[ns], 0, 0, 0);
            acc[ns] = __builtin_amdgcn_mfma_f32_16x16x32_bf16(af1, b1, acc[ns], 0, 0, 0);
        }
    }

    // epilogue: C row = m0 + strip*16 + g4 + r, col n = nhalf*96 + ns*16 + li
#pragma unroll
    for (int ns = 0; ns < 6; ++ns) {
        const int n = nhalf * 96 + ns * 16 + li;
#pragma unroll
        for (int r = 0; r < 4; ++r) {
            const int rowl = strip * 16 + g4 + r;
            u16 bv = f2bf(acc[ns][r]);
            if (n < 64)        qws[(long)(m0 + rowl) * HD + n]        = bv;
            else if (n < 128)  kws[(long)(m0 + rowl) * HD + (n - 64)] = bv;
            else               Vt[rowl][n - 128]                      = bv;
        }
    }
    __syncthreads();
    // transpose v out: vT[(b*64+d)][ (m0&4095) + mg*8 .. +7 ], padded stride
    {
        const int d  = t >> 3;   // 0..63
        const int mg = t & 7;    // 0..7
        union { u16 h[8]; short8 s; } u;
#pragma unroll
        for (int i = 0; i < 8; ++i) u.h[i] = Vt[mg * 8 + i][d];
        u16* dst = vTws + ((long)(b * 64 + d)) * VSTRIDE + (m0 & (SEQ - 1)) + mg * 8;
        *reinterpret_cast<short8*>(dst) = u.s;
    }
}

// ---------------- Flash attention: software-pipelined K-loop ----------------
// 32 q-rows per wave, two 16-row MFMA tiles sharing K/V registers.
// K register double-buffer with STATIC binding: the k-loop is manually
// unrolled x2; kaA/kaB appear only at distinct sequential call sites (never
// selected by a runtime branch — rounds 2-3 proved LLVM merges identical
// `if (p) use(kaA) else use(kaB)` arms into a selected alloca pointer,
// spilling both buffers to scratch). Ps buffer index stays runtime (LDS is
// fine to index dynamically; only REGISTER arrays need static binding).
// K(t+2) issues a full loop body before sphase consumes it.
// Work decomposition: <=16 k-tile chunks -> 1280 blocks, heavy-first.
// XCD-batch affinity: blockIdx%8 = XCD; batch b -> XCDs {2b,2b+1}.
__global__ __launch_bounds__(256, 3) void attn_kernel(
    const u32* __restrict__ xs,
    const u16* __restrict__ qw, const u16* __restrict__ kw,
    const u16* __restrict__ vTw, const u32* __restrict__ maskbits,
    char* __restrict__ part, void* __restrict__ out)
{
    __shared__ __align__(16) char smraw[36864];  // Ps[4][2][2][16][72] u16 / Ow[4][32][64] f32
    __shared__ float lwS[4][32];
    u16   (*Ps)[2][2][16][72] = reinterpret_cast<u16(*)[2][2][16][72]>(smraw);
    float (*Ow)[32][64]       = reinterpret_cast<float(*)[32][64]>(smraw);

    const int flag = sniff_bf16(xs);
    const int t  = threadIdx.x;
    const int l  = t & 63;
    const int w  = t >> 6;
    const int li = l & 15;
    const int g  = l >> 4;
    const int g4 = g * 4;

    // XCD-affine decode: b = (bid%8)>>1; s = per-batch task, heavy first.
    const int bid = blockIdx.x;          // grid = 1280
    const int b   = (bid & 7) >> 1;
    const int s   = (bid >> 3) * 2 + (bid & 1);   // 0..319
    int qt32, c;
    if (s < 128)      { qt32 = 127 - (s >> 2); c = s & 3; }        // 4 chunks
    else if (s < 224) { const int u = s - 128; qt32 = 95 - u / 3; c = u % 3; } // 3
    else if (s < 288) { const int u = s - 224; qt32 = 63 - (u >> 1); c = u & 1; } // 2
    else              { qt32 = 319 - s; c = 0; }                   // 1 chunk
    const int q0    = qt32 * 32;
    const int nkt   = (qt32 >> 1) + 1;
    const int ktBeg = c * 16;
    const int ktEnd = min(ktBeg + 16, nkt);
    const int nc    = (qt32 >= 96) ? 4 : (qt32 >= 64) ? 3 : (qt32 >= 32) ? 2 : 1;

    const u16* qrow = qw + ((long)(b * SEQ + q0 + li)) * HD + g * 8;
    short8 qf0 = *reinterpret_cast<const short8*>(qrow);
    short8 qf1 = *reinterpret_cast<const short8*>(qrow + 32);
    short8 qf2 = *reinterpret_cast<const short8*>(qrow + 16 * HD);
    short8 qf3 = *reinterpret_cast<const short8*>(qrow + 16 * HD + 32);

    short8 ones;
#pragma unroll
    for (int i = 0; i < 8; ++i) ones[i] = (short)0x3F80;  // bf16 1.0

    f32x4 O[8];
#pragma unroll
    for (int i = 0; i < 8; ++i) O[i] = (f32x4){0.f, 0.f, 0.f, 0.f};
    f32x4 l4A = (f32x4){0.f, 0.f, 0.f, 0.f};
    f32x4 l4B = (f32x4){0.f, 0.f, 0.f, 0.f};
    const int qgA = q0 + li;
    const int qgB = q0 + 16 + li;
    const f32x4 z4 = (f32x4){0.f, 0.f, 0.f, 0.f};

    const u16* kbase = kw  + ((long)(b * SEQ) + li) * HD + g * 8;
    const u16* vbase = vTw + ((long)(b * 64)  + li) * VSTRIDE + g * 8;

    const int kt0 = ktBeg + w;
    const int ntile = (kt0 < ktEnd) ? (((ktEnd - kt0) + 3) >> 2) : 0;
    const int toffLast = (ntile - 1) * 4;

    short8 kaA[8], kaB[8];
    short8 vf[8];
    auto kload = [&](short8 (&ka)[8], int toff) {     // clamped prefetch
        const int tt = (toff > toffLast) ? toffLast : toff;
        const u16* kp = kbase + (long)((kt0 + tt) * 64) * HD;
#pragma unroll
        for (int sub = 0; sub < 4; ++sub) {
            ka[2*sub]   = *reinterpret_cast<const short8*>(kp + sub * 16 * HD);
            ka[2*sub+1] = *reinterpret_cast<const short8*>(kp + sub * 16 * HD + 32);
        }
    };
    auto vfload = [&](int it) {
        const int k0 = (kt0 + 4 * it) * 64;
#pragma unroll
        for (int ds = 0; ds < 4; ++ds) {
            const u16* vr = vbase + (long)(ds * 16) * VSTRIDE + k0;
            vf[2*ds]   = *reinterpret_cast<const short8*>(vr);
            vf[2*ds+1] = *reinterpret_cast<const short8*>(vr + 32);
        }
    };
    auto sphase = [&](const short8 (&ka)[8], int toff, int pb) { // S^T+softmax
        const int k0 = (kt0 + toff) * 64;
        const u32 mb0 = maskbits[b * 128 + (k0 >> 5)];
        const u32 mb1 = maskbits[b * 128 + (k0 >> 5) + 1];
#pragma unroll
        for (int sub = 0; sub < 4; ++sub) {
            f32x4 aA = __builtin_amdgcn_mfma_f32_16x16x32_bf16(ka[2*sub],   qf0, z4, 0, 0, 0);
            aA       = __builtin_amdgcn_mfma_f32_16x16x32_bf16(ka[2*sub+1], qf1, aA, 0, 0, 0);
            f32x4 aB = __builtin_amdgcn_mfma_f32_16x16x32_bf16(ka[2*sub],   qf2, z4, 0, 0, 0);
            aB       = __builtin_amdgcn_mfma_f32_16x16x32_bf16(ka[2*sub+1], qf3, aB, 0, 0, 0);
            const u32 word = (sub & 2) ? mb1 : mb0;
            float pA[4], pB[4];
#pragma unroll
            for (int r = 0; r < 4; ++r) {
                const int kloc = sub * 16 + g4 + r;
                const bool bit = ((word >> ((sub & 1) * 16 + g4 + r)) & 1u) != 0u;
                const bool keepA = ((k0 + kloc) <= qgA) && bit;
                const bool keepB = ((k0 + kloc) <= qgB) && bit;
                pA[r] = ex2(fmaf(aA[r], SSCALE, keepA ? CSHIFT : NEGBIG));
                pB[r] = ex2(fmaf(aB[r], SSCALE, keepB ? CSHIFT : NEGBIG));
            }
            *reinterpret_cast<uint2*>(&Ps[w][pb][0][li][sub * 16 + g4]) =
                make_uint2(pkbf(pA[0], pA[1]), pkbf(pA[2], pA[3]));
            *reinterpret_cast<uint2*>(&Ps[w][pb][1][li][sub * 16 + g4]) =
                make_uint2(pkbf(pB[0], pB[1]), pkbf(pB[2], pB[3]));
        }
    };
    auto pvmfma = [&](short8 A1A, short8 A2A, short8 A1B, short8 A2B) {
        f32x4 ltA = __builtin_amdgcn_mfma_f32_16x16x32_bf16(A1A, ones, z4,  0, 0, 0);
        ltA       = __builtin_amdgcn_mfma_f32_16x16x32_bf16(A2A, ones, ltA, 0, 0, 0);
        f32x4 ltB = __builtin_amdgcn_mfma_f32_16x16x32_bf16(A1B, ones, z4,  0, 0, 0);
        ltB       = __builtin_amdgcn_mfma_f32_16x16x32_bf16(A2B, ones, ltB, 0, 0, 0);
#pragma unroll
        for (int r = 0; r < 4; ++r) { l4A[r] += ltA[r]; l4B[r] += ltB[r]; }
#pragma unroll
        for (int ds = 0; ds < 4; ++ds) {
            O[ds]     = __builtin_amdgcn_mfma_f32_16x16x32_bf16(A1A, vf[2*ds],   O[ds],     0, 0, 0);
            O[ds]     = __builtin_amdgcn_mfma_f32_16x16x32_bf16(A2A, vf[2*ds+1], O[ds],     0, 0, 0);
            O[4 + ds] = __builtin_amdgcn_mfma_f32_16x16x32_bf16(A1B, vf[2*ds],   O[4 + ds], 0, 0, 0);
            O[4 + ds] = __builtin_amdgcn_mfma_f32_16x16x32_bf16(A2B, vf[2*ds+1], O[4 + ds], 0, 0, 0);
        }
    };

    if (ntile > 0) {
        kload(kaA, 0);          // K(0)
        kload(kaB, 4);          // K(1) — both issued before first wait
        sphase(kaA, 0, 0);      // P(0) -> Ps[0]
    }
    int i = 0;
    for (; i + 2 <= ntile; i += 2) {
        {   // tile i (even): Ps[0] ready, kaB holds K(i+1)
            vfload(i);
            short8 A1A = *reinterpret_cast<const short8*>(&Ps[w][0][0][li][g * 8]);
            short8 A2A = *reinterpret_cast<const short8*>(&Ps[w][0][0][li][32 + g * 8]);
            short8 A1B = *reinterpret_cast<const short8*>(&Ps[w][0][1][li][g * 8]);
            short8 A2B = *reinterpret_cast<const short8*>(&Ps[w][0][1][li][32 + g * 8]);
            sphase(kaB, 4 * (i + 1), 1);     // always valid: i+1 < ntile
            kload(kaA, 4 * (i + 2));         // K(i+2), clamped
            pvmfma(A1A, A2A, A1B, A2B);
        }
        {   // tile i+1 (odd): Ps[1] ready, kaA holds K(i+2)
            vfload(i + 1);
            short8 A1A = *reinterpret_cast<const short8*>(&Ps[w][1][0][li][g * 8]);
            short8 A2A = *reinterpret_cast<const short8*>(&Ps[w][1][0][li][32 + g * 8]);
            short8 A1B = *reinterpret_cast<const short8*>(&Ps[w][1][1][li][g * 8]);
            short8 A2B = *reinterpret_cast<const short8*>(&Ps[w][1][1][li][32 + g * 8]);
            if (i + 2 < ntile) {
                sphase(kaA, 4 * (i + 2), 0); // P(i+2) -> Ps[0]
                kload(kaB, 4 * (i + 3));     // K(i+3), clamped
            }
            pvmfma(A1A, A2A, A1B, A2B);
        }
    }
    if (i < ntile) {            // leftover even tile: Ps[0] ready
        vfload(i);
        short8 A1A = *reinterpret_cast<const short8*>(&Ps[w][0][0][li][g * 8]);
        short8 A2A = *reinterpret_cast<const short8*>(&Ps[w][0][0][li][32 + g * 8]);
        short8 A1B = *reinterpret_cast<const short8*>(&Ps[w][0][1][li][g * 8]);
        short8 A2B = *reinterpret_cast<const short8*>(&Ps[w][0][1][li][32 + g * 8]);
        pvmfma(A1A, A2A, A1B, A2B);
    }

    __syncthreads();   // all Ps reads done before Ow overlay writes
#pragma unroll
    for (int tile = 0; tile < 2; ++tile)
#pragma unroll
        for (int ds = 0; ds < 4; ++ds)
#pragma unroll
            for (int r = 0; r < 4; ++r)
                Ow[w][tile * 16 + g4 + r][ds * 16 + li] = O[tile * 4 + ds][r];
    if (li == 0) {
#pragma unroll
        for (int r = 0; r < 4; ++r) {
            lwS[w][g4 + r]      = l4A[r];
            lwS[w][16 + g4 + r] = l4B[r];
        }
    }
    __syncthreads();

    // combine 4 wave partials; thread -> (q = t>>3, d = (t&7)*8 .. +7)
    {
        const int qq = t >> 3;          // 0..31
        const int dd = (t & 7) * 8;     // 0..56
        float L = lwS[0][qq] + lwS[1][qq] + lwS[2][qq] + lwS[3][qq];
        float a8[8];
#pragma unroll
        for (int j = 0; j < 8; ++j) a8[j] = 0.f;
#pragma unroll
        for (int wv = 0; wv < 4; ++wv) {
            float4 o0 = *reinterpret_cast<const float4*>(&Ow[wv][qq][dd]);
            float4 o1 = *reinterpret_cast<const float4*>(&Ow[wv][qq][dd + 4]);
            a8[0] += o0.x; a8[1] += o0.y; a8[2] += o0.z; a8[3] += o0.w;
            a8[4] += o1.x; a8[5] += o1.y; a8[6] += o1.z; a8[7] += o1.w;
        }
        if (nc == 1) {
            const float rl = (L > 0.f) ? 1.f / L : 0.f;
#pragma unroll
            for (int j = 0; j < 8; ++j) a8[j] *= rl;
            const long row = (long)(b * SEQ + q0 + qq);
            if (flag) {
                uint4 st = make_uint4(pkbf(a8[0], a8[1]), pkbf(a8[2], a8[3]),
                                      pkbf(a8[4], a8[5]), pkbf(a8[6], a8[7]));
                *reinterpret_cast<uint4*>((u16*)out + row * HD + dd) = st;
            } else {
                *reinterpret_cast<float4*>((float*)out + row * HD + dd) =
                    make_float4(a8[0], a8[1], a8[2], a8[3]);
                *reinterpret_cast<float4*>((float*)out + row * HD + dd + 4) =
                    make_float4(a8[4], a8[5], a8[6], a8[7]);
            }
        } else {
            char* slot = part + ((long)((b * 96 + (qt32 - 32)) * 4 + c)) * PSLOTB;
            uint4 st = make_uint4(pkbf(a8[0], a8[1]), pkbf(a8[2], a8[3]),
                                  pkbf(a8[4], a8[5]), pkbf(a8[6], a8[7]));
            *reinterpret_cast<uint4*>((u16*)slot + qq * 64 + dd) = st;
            if ((t & 7) == 0)
                *reinterpret_cast<float*>(slot + 4096 + qq * 4) = L;
        }
    }
}

// ---------------- merge split-K partials (qt32 >= 32): plain sum ----------
__global__ __launch_bounds__(256) void merge_kernel(
    const u32* __restrict__ xs, const char* __restrict__ part,
    void* __restrict__ out)
{
    const int flag = sniff_bf16(xs);
    const int bid = blockIdx.x;         // 384
    const int b    = bid & 3;
    const int qt32 = 32 + (bid >> 2);
    const int nc   = (qt32 >= 96) ? 4 : (qt32 >= 64) ? 3 : 2;
    const int t  = threadIdx.x;
    const int qq = t >> 3;              // 0..31
    const int dd = (t & 7) * 8;         // 0..56
    const char* s0 = part + ((long)((b * 96 + (qt32 - 32)) * 4)) * PSLOTB;
    float L = 0.f;
    float a8[8];
#pragma unroll
    for (int j = 0; j < 8; ++j) a8[j] = 0.f;
    for (int c = 0; c < nc; ++c) {
        const char* sc = s0 + (long)c * PSLOTB;
        L += *reinterpret_cast<const float*>(sc + 4096 + qq * 4);
        ushort4 x0 = *reinterpret_cast<const ushort4*>((const u16*)sc + qq * 64 + dd);
        ushort4 x1 = *reinterpret_cast<const ushort4*>((const u16*)sc + qq * 64 + dd + 4);
        a8[0] += bfbits2f(x0.x); a8[1] += bfbits2f(x0.y);
        a8[2] += bfbits2f(x0.z); a8[3] += bfbits2f(x0.w);
        a8[4] += bfbits2f(x1.x); a8[5] += bfbits2f(x1.y);
        a8[6] += bfbits2f(x1.z); a8[7] += bfbits2f(x1.w);
    }
    const float rl = (L > 0.f) ? 1.f / L : 0.f;
#pragma unroll
    for (int j = 0; j < 8; ++j) a8[j] *= rl;
    const long row = (long)(b * SEQ + qt32 * 32 + qq);
    if (flag) {
        uint4 st = make_uint4(pkbf(a8[0], a8[1]), pkbf(a8[2], a8[3]),
                              pkbf(a8[4], a8[5]), pkbf(a8[6], a8[7]));
        *reinterpret_cast<uint4*>((u16*)out + row * HD + dd) = st;
    } else {
        *reinterpret_cast<float4*>((float*)out + row * HD + dd) =
            make_float4(a8[0], a8[1], a8[2], a8[3]);
        *reinterpret_cast<float4*>((float*)out + row * HD + dd + 4) =
            make_float4(a8[4], a8[5], a8[6], a8[7]);
    }
}

extern "C" void kernel_launch(void* const* d_in, const int* in_sizes, int n_in,
                              void* d_out, int out_size, void* d_ws, size_t ws_size,
                              hipStream_t stream) {
    const void* x   = d_in[0];
    const int* mask = (const int*)d_in[1];
    const void* wq  = d_in[2];
    const void* wk  = d_in[3];
    const void* wv  = d_in[4];
    const u32* xs   = (const u32*)x;

    u16* q    = (u16*)d_ws;                          // 2 MB
    u16* k    = q  + (long)NROW * HD;                // 2 MB
    u16* vT   = k  + (long)NROW * HD;                // 2.16 MB
    u32* mb   = (u32*)(vT + (long)BATCH * 64 * VSTRIDE);  // 2 KB
    char* part = (char*)(mb + 512);                  // 6.49 MB (1536 slots)
    u16* wb   = (u16*)(part + (long)1536 * PSLOTB);  // 288 KB bf16 W

    wconv_kernel<<<72, 256, 0, stream>>>(xs, wq, wk, wv, wb);
    qkv_kernel  <<<258, 512, 0, stream>>>(x, wb, mask, q, k, vT, mb);
    attn_kernel <<<1280, 256, 0, stream>>>(xs, q, k, vT, mb, part, d_out);
    merge_kernel<<<384, 256, 0, stream>>>(xs, part, d_out);
}

// Round 6
// 162.047 us; speedup vs baseline: 1.0587x; 1.0587x over previous
//
#include <hip/hip_runtime.h>
#include <hip/hip_bf16.h>

typedef unsigned int u32;
typedef unsigned short u16;
typedef unsigned long long u64;
typedef __attribute__((ext_vector_type(8))) short short8;
typedef __attribute__((ext_vector_type(4))) float f32x4;

#define BATCH 4
#define SEQ   4096
#define DIM   768
#define HD    64
#define NROW  (BATCH*SEQ)   // 16384
#define LOG2E 1.44269504088896f
#define SSCALE (0.125f * LOG2E)
#define CSHIFT (-32.0f)      // fixed exp2-domain shift (softmax shift-invariant)
#define NEGBIG (-1.0e30f)
#define VSTRIDE 4224         // vT row stride in u16 (breaks L2 channel camping)
#define PSLOTB 4224          // partial slot: 4096 B bf16 O[32][64] + 128 B f32 l[32]
#define NSLOT  2240          // 4 batches x 140 chunk-slots x 4 waves

__device__ __forceinline__ float ex2(float x) { return __builtin_amdgcn_exp2f(x); }
__device__ __forceinline__ float bfbits2f(u16 u) {
    return __uint_as_float(((u32)u) << 16);
}
__device__ __forceinline__ u16 f2bf(float f) {
    return (u16)((__float_as_uint(f) + 0x8000u) >> 16);
}
__device__ __forceinline__ u32 pkbf(float a, float b) { // lo16=bf(a), hi16=bf(b)
    u32 xa = __float_as_uint(a) + 0x8000u;
    u32 xb = __float_as_uint(b) + 0x8000u;
    return __builtin_amdgcn_perm(xb, xa, 0x07060302);
}
// Deterministic per-wave dtype sniff (same answer in every wave/block).
__device__ __forceinline__ int sniff_bf16(const u32* x) {
    u32 w = x[threadIdx.x & 63];
    u32 lo = w & 0xffffu;
    u32 e  = (lo >> 7) & 0xffu;
    bool ok = (lo == 0u) || (e >= 96u && e <= 134u);
    u64 bal = __ballot(ok);
    return (__popcll(bal) >= 48) ? 1 : 0;
}
// packed chunk-slot offset for qt128 >= 4: bands of 4 tiles, band k = qt128>>2
// has k+1 chunks each. off = 2k^2+2k-4 + (qt128&3)*(k+1). Total 140 per batch.
__device__ __forceinline__ int chunk_off(int qt128) {
    const int k = qt128 >> 2;
    return 2*k*k + 2*k - 4 + (qt128 & 3) * (k + 1);
}

// ---------------- W pre-conversion: fp32 -> bf16, ONCE ---------------------
__global__ __launch_bounds__(256) void wconv_kernel(
    const u32* __restrict__ xs,
    const void* __restrict__ wq, const void* __restrict__ wk,
    const void* __restrict__ wv, u16* __restrict__ wb)
{
    const int flag = sniff_bf16(xs);
    const int j = blockIdx.x * 256 + threadIdx.x;   // 0..18431
    const int e = j * 8;
    const int r = e / DIM;          // 0..191  ([wq;wk;wv] stacked)
    const int c = e - r * DIM;
    const void* src = (r < 64) ? wq : (r < 128) ? wk : wv;
    const long soff = (long)(r & 63) * DIM + c;
    if (flag) {
        *reinterpret_cast<short8*>(wb + (long)r * DIM + c) =
            *reinterpret_cast<const short8*>((const u16*)src + soff);
    } else {
        const float* p = (const float*)src + soff;
        float4 a = *reinterpret_cast<const float4*>(p);
        float4 d = *reinterpret_cast<const float4*>(p + 4);
        union { u32 u[4]; short8 s; } un;
        un.u[0] = pkbf(a.x, a.y); un.u[1] = pkbf(a.z, a.w);
        un.u[2] = pkbf(d.x, d.y); un.u[3] = pkbf(d.z, d.w);
        *reinterpret_cast<short8*>(wb + (long)r * DIM + c) = un.s;
    }
}

// ---------------- QKV projection: LDS-tiled GEMM (m97 shape) ----------------
__global__ __launch_bounds__(512, 4) void qkv_kernel(
    const void* __restrict__ x, const u16* __restrict__ wb,
    const int* __restrict__ mask,
    u16* __restrict__ qws, u16* __restrict__ kws, u16* __restrict__ vTws,
    u32* __restrict__ mb)
{
    const int t = threadIdx.x;
    const int l = t & 63;
    const int w = t >> 6;

    if (blockIdx.x >= 256) {            // ---- mask bit-pack ----
        const int base = (blockIdx.x - 256) * 8192 + w * 1024;
#pragma unroll
        for (int it = 0; it < 16; ++it) {
            const int idx = base + it * 64 + l;
            u64 bal = __ballot(mask[idx] != 0);
            if (l == 0)       mb[idx >> 5] = (u32)bal;
            else if (l == 32) mb[idx >> 5] = (u32)(bal >> 32);
        }
        return;
    }

    const int flag = sniff_bf16((const u32*)x);
    __shared__ __align__(16) u16 Xl[64 * 64];    // 8 KB,  slot r*64 + cc*8
    __shared__ __align__(16) u16 Wl[192 * 64];   // 24 KB, slot n*64 + cc*8
    __shared__ u16 Vt[64][66];                   // 8.4 KB transpose staging

    const int li = l & 15;
    const int g  = l >> 4;
    const int g4 = g * 4;
    const int strip = w & 3;            // 16-row strip
    const int nhalf = w >> 2;           // 96-col half
    const int m0 = blockIdx.x * 64;
    const int b  = m0 >> 12;

    auto ldbf = [&](const void* bp, long off) -> short8 {
        if (flag) return *reinterpret_cast<const short8*>((const u16*)bp + off);
        const float* p = (const float*)bp + off;
        float4 a = *reinterpret_cast<const float4*>(p);
        float4 c = *reinterpret_cast<const float4*>(p + 4);
        union { u32 u[4]; short8 s; } un;
        un.u[0] = pkbf(a.x, a.y); un.u[1] = pkbf(a.z, a.w);
        un.u[2] = pkbf(c.x, c.y); un.u[3] = pkbf(c.z, c.w);
        return un.s;
    };

    const int xr = t >> 3, xcc = t & 7, xc = xcc ^ (xr & 7);
    const long xsoff = (long)(m0 + xr) * DIM + xc * 8;
    long wboff[3]; int wdst[3];
#pragma unroll
    for (int j = 0; j < 3; ++j) {
        const int idx = j * 512 + t;
        const int r = idx >> 3, cc = idx & 7, c = cc ^ (r & 7);
        wboff[j] = (long)r * DIM + c * 8;     // r = 0..191 into stacked wb
        wdst[j]  = idx * 8;                   // u16 offset into Wl
    }

    const int am = strip * 16 + li;
    const int a0off = am * 64 + ((g       ^ (am & 7)) * 8);
    const int a1off = am * 64 + (((g | 4) ^ (am & 7)) * 8);
    int boff[12];
#pragma unroll
    for (int ns = 0; ns < 6; ++ns) {
        const int n = nhalf * 96 + ns * 16 + li;
        boff[2*ns]   = n * 64 + ((g       ^ (n & 7)) * 8);
        boff[2*ns+1] = n * 64 + (((g | 4) ^ (n & 7)) * 8);
    }

    f32x4 acc[6];
#pragma unroll
    for (int i = 0; i < 6; ++i) acc[i] = (f32x4){0.f, 0.f, 0.f, 0.f};

    short8 xs  = ldbf(x, xsoff);
    short8 ws0 = *reinterpret_cast<const short8*>(wb + wboff[0]);
    short8 ws1 = *reinterpret_cast<const short8*>(wb + wboff[1]);
    short8 ws2 = *reinterpret_cast<const short8*>(wb + wboff[2]);

    for (int kc = 0; kc < 12; ++kc) {
        __syncthreads();                 // previous K-step's LDS reads done
        *reinterpret_cast<short8*>(&Xl[t * 8])    = xs;
        *reinterpret_cast<short8*>(&Wl[wdst[0]])  = ws0;
        *reinterpret_cast<short8*>(&Wl[wdst[1]])  = ws1;
        *reinterpret_cast<short8*>(&Wl[wdst[2]])  = ws2;
        if (kc < 11) {                   // prefetch next staging tile
            const long o = (long)(kc + 1) * 64;
            xs  = ldbf(x, xsoff + o);
            ws0 = *reinterpret_cast<const short8*>(wb + wboff[0] + o);
            ws1 = *reinterpret_cast<const short8*>(wb + wboff[1] + o);
            ws2 = *reinterpret_cast<const short8*>(wb + wboff[2] + o);
        }
        __syncthreads();                 // staging visible
        short8 af0 = *reinterpret_cast<const short8*>(&Xl[a0off]);
        short8 af1 = *reinterpret_cast<const short8*>(&Xl[a1off]);
#pragma unroll
        for (int ns = 0; ns < 6; ++ns) {
            short8 b0 = *reinterpret_cast<const short8*>(&Wl[boff[2*ns]]);
            short8 b1 = *reinterpret_cast<const short8*>(&Wl[boff[2*ns+1]]);
            acc[ns] = __builtin_amdgcn_mfma_f32_16x16x32_bf16(af0, b0, acc[ns], 0, 0, 0);
            acc[ns] = __builtin_amdgcn_mfma_f32_16x16x32_bf16(af1, b1, acc[ns], 0, 0, 0);
        }
    }

#pragma unroll
    for (int ns = 0; ns < 6; ++ns) {
        const int n = nhalf * 96 + ns * 16 + li;
#pragma unroll
        for (int r = 0; r < 4; ++r) {
            const int rowl = strip * 16 + g4 + r;
            u16 bv = f2bf(acc[ns][r]);
            if (n < 64)        qws[(long)(m0 + rowl) * HD + n]        = bv;
            else if (n < 128)  kws[(long)(m0 + rowl) * HD + (n - 64)] = bv;
            else               Vt[rowl][n - 128]                      = bv;
        }
    }
    __syncthreads();
    {
        const int d  = t >> 3;   // 0..63
        const int mg = t & 7;    // 0..7
        union { u16 h[8]; short8 s; } u;
#pragma unroll
        for (int i = 0; i < 8; ++i) u.h[i] = Vt[mg * 8 + i][d];
        u16* dst = vTws + ((long)(b * 64 + d)) * VSTRIDE + (m0 & (SEQ - 1)) + mg * 8;
        *reinterpret_cast<short8*>(dst) = u.s;
    }
}

// ---------------- Flash attention: shared-k-tile convoy ----------------
// NEW decomposition: block = 128 q-rows (qt128), 4 waves each own 32 q-rows
// (q0 = qt128*128 + w*32). ALL waves walk the SAME k-tile sequence, convoy-
// aligned by a raw s_barrier (no vmcnt drain -> prefetches stay in flight).
// The 4 waves' identical K/V loads are served by L1 (16 KB tile < 32 KB) +
// MSHR merge: L2 K/V traffic drops ~4x (266 -> ~70-90 MB). Rationale: r0/r1/
// r4 times track K/V L2 bytes at ~5 TB/s (traffic-bound, not latency-bound:
// r4's 4x-parallelism change at constant traffic was a no-op).
// Inner pipeline = round-4's proven single-ka structure (84 VGPR, no spill).
// NO cross-wave combine anymore (waves own disjoint rows): per-wave epilogue
// stages O through its private Ps region, writes out/partial directly.
// Chunks of <=8 k-tiles -> 576 blocks, heavy-first, XCD-affine (bid%8=XCD,
// batch b -> XCDs {2b,2b+1}).
__global__ __launch_bounds__(256, 3) void attn_kernel(
    const u32* __restrict__ xs,
    const u16* __restrict__ qw, const u16* __restrict__ kw,
    const u16* __restrict__ vTw, const u32* __restrict__ maskbits,
    char* __restrict__ part, void* __restrict__ out)
{
    __shared__ __align__(16) u16 Ps[4][2][2][16][72];   // 36.9 KB, per-wave regions

    const int flag = sniff_bf16(xs);
    const int t  = threadIdx.x;
    const int l  = t & 63;
    const int w  = t >> 6;
    const int li = l & 15;
    const int g  = l >> 4;
    const int g4 = g * 4;

    // XCD-affine decode: b = (bid%8)>>1; s = per-batch task, heavy first.
    const int bid = blockIdx.x;          // grid = 576
    const int b   = (bid & 7) >> 1;
    const int s   = (bid >> 3) * 2 + (bid & 1);   // 0..143
    int qt128, c;
    if      (s < 32)  { qt128 = 31 - (s >> 3);         c = s & 7;  }  // 8 chunks
    else if (s < 60)  { const int u = s - 32;  qt128 = 27 - u / 7; c = u % 7; }
    else if (s < 84)  { const int u = s - 60;  qt128 = 23 - u / 6; c = u % 6; }
    else if (s < 104) { const int u = s - 84;  qt128 = 19 - u / 5; c = u % 5; }
    else if (s < 120) { const int u = s - 104; qt128 = 15 - (u >> 2); c = u & 3; }
    else if (s < 132) { const int u = s - 120; qt128 = 11 - u / 3; c = u % 3; }
    else if (s < 140) { const int u = s - 132; qt128 = 7 - (u >> 1); c = u & 1; }
    else              { qt128 = 3 - (s - 140);         c = 0;  }      // 1 chunk
    const int nkt    = 2 * qt128 + 2;
    const int ktBeg  = c * 8;
    const int ktEnd  = min(ktBeg + 8, nkt);
    const int ntile  = ktEnd - ktBeg;            // 1..8, uniform across waves
    const bool single = (qt128 < 4);             // 1 chunk -> direct out write
    const int q0     = qt128 * 128 + w * 32;     // this wave's q rows

    const u16* qrow = qw + ((long)(b * SEQ + q0 + li)) * HD + g * 8;
    short8 qf0 = *reinterpret_cast<const short8*>(qrow);
    short8 qf1 = *reinterpret_cast<const short8*>(qrow + 32);
    short8 qf2 = *reinterpret_cast<const short8*>(qrow + 16 * HD);
    short8 qf3 = *reinterpret_cast<const short8*>(qrow + 16 * HD + 32);

    short8 ones;
#pragma unroll
    for (int i = 0; i < 8; ++i) ones[i] = (short)0x3F80;  // bf16 1.0

    f32x4 O[8];
#pragma unroll
    for (int i = 0; i < 8; ++i) O[i] = (f32x4){0.f, 0.f, 0.f, 0.f};
    f32x4 l4A = (f32x4){0.f, 0.f, 0.f, 0.f};
    f32x4 l4B = (f32x4){0.f, 0.f, 0.f, 0.f};
    const int qgA = q0 + li;
    const int qgB = q0 + 16 + li;
    const f32x4 z4 = (f32x4){0.f, 0.f, 0.f, 0.f};

    const u16* kbase = kw  + ((long)(b * SEQ) + li) * HD + g * 8;
    const u16* vbase = vTw + ((long)(b * 64)  + li) * VSTRIDE + g * 8;
    const int tLast = ntile - 1;

    short8 ka[8];
    short8 vf[8];
    auto kload = [&](int i) {                     // clamped prefetch, tile idx
        const int tt = (i > tLast) ? tLast : i;
        const u16* kp = kbase + (long)((ktBeg + tt) * 64) * HD;
#pragma unroll
        for (int sub = 0; sub < 4; ++sub) {
            ka[2*sub]   = *reinterpret_cast<const short8*>(kp + sub * 16 * HD);
            ka[2*sub+1] = *reinterpret_cast<const short8*>(kp + sub * 16 * HD + 32);
        }
    };
    auto vfload = [&](int i) {
        const int k0 = (ktBeg + i) * 64;
#pragma unroll
        for (int ds = 0; ds < 4; ++ds) {
            const u16* vr = vbase + (long)(ds * 16) * VSTRIDE + k0;
            vf[2*ds]   = *reinterpret_cast<const short8*>(vr);
            vf[2*ds+1] = *reinterpret_cast<const short8*>(vr + 32);
        }
    };
    auto sphase = [&](int i, int pb) {            // S^T + softmax -> Ps[w][pb]
        const int k0 = (ktBeg + i) * 64;
        const u32 mb0 = maskbits[b * 128 + (k0 >> 5)];
        const u32 mb1 = maskbits[b * 128 + (k0 >> 5) + 1];
#pragma unroll
        for (int sub = 0; sub < 4; ++sub) {
            f32x4 aA = __builtin_amdgcn_mfma_f32_16x16x32_bf16(ka[2*sub],   qf0, z4, 0, 0, 0);
            aA       = __builtin_amdgcn_mfma_f32_16x16x32_bf16(ka[2*sub+1], qf1, aA, 0, 0, 0);
            f32x4 aB = __builtin_amdgcn_mfma_f32_16x16x32_bf16(ka[2*sub],   qf2, z4, 0, 0, 0);
            aB       = __builtin_amdgcn_mfma_f32_16x16x32_bf16(ka[2*sub+1], qf3, aB, 0, 0, 0);
            const u32 word = (sub & 2) ? mb1 : mb0;
            float pA[4], pB[4];
#pragma unroll
            for (int r = 0; r < 4; ++r) {
                const int kloc = sub * 16 + g4 + r;
                const bool bit = ((word >> ((sub & 1) * 16 + g4 + r)) & 1u) != 0u;
                const bool keepA = ((k0 + kloc) <= qgA) && bit;
                const bool keepB = ((k0 + kloc) <= qgB) && bit;
                pA[r] = ex2(fmaf(aA[r], SSCALE, keepA ? CSHIFT : NEGBIG));
                pB[r] = ex2(fmaf(aB[r], SSCALE, keepB ? CSHIFT : NEGBIG));
            }
            *reinterpret_cast<uint2*>(&Ps[w][pb][0][li][sub * 16 + g4]) =
                make_uint2(pkbf(pA[0], pA[1]), pkbf(pA[2], pA[3]));
            *reinterpret_cast<uint2*>(&Ps[w][pb][1][li][sub * 16 + g4]) =
                make_uint2(pkbf(pB[0], pB[1]), pkbf(pB[2], pB[3]));
        }
    };

    kload(0);
    sphase(0, 0);
    kload(1);
    for (int i = 0; i < ntile; ++i) {
        __builtin_amdgcn_s_barrier();   // convoy: keep 4 waves on same tile
        vfload(i);
        short8 A1A = *reinterpret_cast<const short8*>(&Ps[w][i & 1][0][li][g * 8]);
        short8 A2A = *reinterpret_cast<const short8*>(&Ps[w][i & 1][0][li][32 + g * 8]);
        short8 A1B = *reinterpret_cast<const short8*>(&Ps[w][i & 1][1][li][g * 8]);
        short8 A2B = *reinterpret_cast<const short8*>(&Ps[w][i & 1][1][li][32 + g * 8]);
        if (i + 1 < ntile) {
            sphase(i + 1, (i & 1) ^ 1);  // consumes ka loaded last iter
            kload(i + 2);                // refill single buffer (clamped)
        }
        f32x4 ltA = __builtin_amdgcn_mfma_f32_16x16x32_bf16(A1A, ones, z4,  0, 0, 0);
        ltA       = __builtin_amdgcn_mfma_f32_16x16x32_bf16(A2A, ones, ltA, 0, 0, 0);
        f32x4 ltB = __builtin_amdgcn_mfma_f32_16x16x32_bf16(A1B, ones, z4,  0, 0, 0);
        ltB       = __builtin_amdgcn_mfma_f32_16x16x32_bf16(A2B, ones, ltB, 0, 0, 0);
#pragma unroll
        for (int r = 0; r < 4; ++r) { l4A[r] += ltA[r]; l4B[r] += ltB[r]; }
#pragma unroll
        for (int ds = 0; ds < 4; ++ds) {
            O[ds]     = __builtin_amdgcn_mfma_f32_16x16x32_bf16(A1A, vf[2*ds],   O[ds],     0, 0, 0);
            O[ds]     = __builtin_amdgcn_mfma_f32_16x16x32_bf16(A2A, vf[2*ds+1], O[ds],     0, 0, 0);
            O[4 + ds] = __builtin_amdgcn_mfma_f32_16x16x32_bf16(A1B, vf[2*ds],   O[4 + ds], 0, 0, 0);
            O[4 + ds] = __builtin_amdgcn_mfma_f32_16x16x32_bf16(A2B, vf[2*ds+1], O[4 + ds], 0, 0, 0);
        }
    }

    // ---- per-wave epilogue: stage O,L through this wave's Ps region ----
    // Of[32][stride 66] f32 (8448 B) + Lf[32] f32 (128 B) fit in 9216 B.
    {
        float* Of = reinterpret_cast<float*>(&Ps[w][0][0][0][0]);
        float* Lf = Of + 2112;
#pragma unroll
        for (int tile = 0; tile < 2; ++tile)
#pragma unroll
            for (int ds = 0; ds < 4; ++ds)
#pragma unroll
                for (int r = 0; r < 4; ++r)
                    Of[(tile * 16 + g4 + r) * 66 + ds * 16 + li] = O[tile * 4 + ds][r];
        if (li == 0) {
#pragma unroll
            for (int r = 0; r < 4; ++r) {
                Lf[g4 + r]      = l4A[r];
                Lf[16 + g4 + r] = l4B[r];
            }
        }
        const int r32 = l >> 1;          // 0..31: output row within wave
        const int h   = l & 1;           // column half (32 cols)
        float v[32];
#pragma unroll
        for (int j = 0; j < 8; ++j) {
            float4 f = *reinterpret_cast<const float4*>(&Of[r32 * 66 + h * 32 + j * 4]);
            v[4*j] = f.x; v[4*j+1] = f.y; v[4*j+2] = f.z; v[4*j+3] = f.w;
        }
        if (single) {
            const float L = Lf[r32];
            const float rl = (L > 0.f) ? 1.f / L : 0.f;
#pragma unroll
            for (int j = 0; j < 32; ++j) v[j] *= rl;
            const long row = (long)(b * SEQ + q0 + r32);
            if (flag) {
                u16* dst = (u16*)out + row * HD + h * 32;
#pragma unroll
                for (int jj = 0; jj < 4; ++jj) {
                    uint4 st = make_uint4(pkbf(v[8*jj],   v[8*jj+1]), pkbf(v[8*jj+2], v[8*jj+3]),
                                          pkbf(v[8*jj+4], v[8*jj+5]), pkbf(v[8*jj+6], v[8*jj+7]));
                    *reinterpret_cast<uint4*>(dst + jj * 8) = st;
                }
            } else {
                float* dst = (float*)out + row * HD + h * 32;
#pragma unroll
                for (int jj = 0; jj < 8; ++jj)
                    *reinterpret_cast<float4*>(dst + jj * 4) =
                        make_float4(v[4*jj], v[4*jj+1], v[4*jj+2], v[4*jj+3]);
            }
        } else {
            const int slotIdx = ((b * 140 + chunk_off(qt128) + c) * 4 + w);
            char* slot = part + (long)slotIdx * PSLOTB;
            u16* dst = (u16*)slot + r32 * 64 + h * 32;
#pragma unroll
            for (int jj = 0; jj < 4; ++jj) {
                uint4 st = make_uint4(pkbf(v[8*jj],   v[8*jj+1]), pkbf(v[8*jj+2], v[8*jj+3]),
                                      pkbf(v[8*jj+4], v[8*jj+5]), pkbf(v[8*jj+6], v[8*jj+7]));
                *reinterpret_cast<uint4*>(dst + jj * 8) = st;
            }
            if (l < 32)
                *reinterpret_cast<float*>(slot + 4096 + l * 4) = Lf[l];
        }
    }
}

// ---------------- merge split-K partials (qt32 >= 16): plain sum ----------
__global__ __launch_bounds__(256) void merge_kernel(
    const u32* __restrict__ xs, const char* __restrict__ part,
    void* __restrict__ out)
{
    const int flag = sniff_bf16(xs);
    const int bid = blockIdx.x;         // 448
    const int b     = bid & 3;
    const int qt32  = 16 + (bid >> 2);  // 16..127
    const int qt128 = qt32 >> 2;
    const int k     = qt128 >> 2;
    const int nc    = k + 1;            // 2..8 chunks
    const int t  = threadIdx.x;
    const int qq = t >> 3;              // 0..31
    const int dd = (t & 7) * 8;         // 0..56
    const char* s0 = part +
        ((long)((b * 140 + chunk_off(qt128)) * 4 + (qt32 & 3))) * PSLOTB;
    float L = 0.f;
    float a8[8];
#pragma unroll
    for (int j = 0; j < 8; ++j) a8[j] = 0.f;
    for (int c = 0; c < nc; ++c) {
        const char* sc = s0 + (long)c * 4 * PSLOTB;   // c-stride = 4 slots
        L += *reinterpret_cast<const float*>(sc + 4096 + qq * 4);
        ushort4 x0 = *reinterpret_cast<const ushort4*>((const u16*)sc + qq * 64 + dd);
        ushort4 x1 = *reinterpret_cast<const ushort4*>((const u16*)sc + qq * 64 + dd + 4);
        a8[0] += bfbits2f(x0.x); a8[1] += bfbits2f(x0.y);
        a8[2] += bfbits2f(x0.z); a8[3] += bfbits2f(x0.w);
        a8[4] += bfbits2f(x1.x); a8[5] += bfbits2f(x1.y);
        a8[6] += bfbits2f(x1.z); a8[7] += bfbits2f(x1.w);
    }
    const float rl = (L > 0.f) ? 1.f / L : 0.f;
#pragma unroll
    for (int j = 0; j < 8; ++j) a8[j] *= rl;
    const long row = (long)(b * SEQ + qt32 * 32 + qq);
    if (flag) {
        uint4 st = make_uint4(pkbf(a8[0], a8[1]), pkbf(a8[2], a8[3]),
                              pkbf(a8[4], a8[5]), pkbf(a8[6], a8[7]));
        *reinterpret_cast<uint4*>((u16*)out + row * HD + dd) = st;
    } else {
        *reinterpret_cast<float4*>((float*)out + row * HD + dd) =
            make_float4(a8[0], a8[1], a8[2], a8[3]);
        *reinterpret_cast<float4*>((float*)out + row * HD + dd + 4) =
            make_float4(a8[4], a8[5], a8[6], a8[7]);
    }
}

extern "C" void kernel_launch(void* const* d_in, const int* in_sizes, int n_in,
                              void* d_out, int out_size, void* d_ws, size_t ws_size,
                              hipStream_t stream) {
    const void* x   = d_in[0];
    const int* mask = (const int*)d_in[1];
    const void* wq  = d_in[2];
    const void* wk  = d_in[3];
    const void* wv  = d_in[4];
    const u32* xs   = (const u32*)x;

    u16* q    = (u16*)d_ws;                          // 2 MB
    u16* k    = q  + (long)NROW * HD;                // 2 MB
    u16* vT   = k  + (long)NROW * HD;                // 2.16 MB
    u32* mb   = (u32*)(vT + (long)BATCH * 64 * VSTRIDE);  // 2 KB
    char* part = (char*)(mb + 512);                  // 2240 slots = 9.46 MB
    u16* wb   = (u16*)(part + (long)NSLOT * PSLOTB); // 288 KB bf16 W

    wconv_kernel<<<72, 256, 0, stream>>>(xs, wq, wk, wv, wb);
    qkv_kernel  <<<258, 512, 0, stream>>>(x, wb, mask, q, k, vT, mb);
    attn_kernel <<<576, 256, 0, stream>>>(xs, q, k, vT, mb, part, d_out);
    merge_kernel<<<448, 256, 0, stream>>>(xs, part, d_out);
}

// Round 7
// 146.260 us; speedup vs baseline: 1.1730x; 1.1079x over previous
//
#include <hip/hip_runtime.h>
#include <hip/hip_bf16.h>

typedef unsigned int u32;
typedef unsigned short u16;
typedef unsigned long long u64;
typedef __attribute__((ext_vector_type(8))) short short8;
typedef __attribute__((ext_vector_type(4))) float f32x4;

#define BATCH 4
#define SEQ   4096
#define DIM   768
#define HD    64
#define NROW  (BATCH*SEQ)   // 16384
#define LOG2E 1.44269504088896f
#define SSCALE (0.125f * LOG2E)
#define CSHIFT (-32.0f)      // fixed exp2-domain shift (softmax shift-invariant)
#define NEGBIG (-1.0e30f)
#define VSTRIDE 4224         // vT row stride in u16 (breaks L2 channel camping)
#define PSLOTB 4224          // partial slot: 4096 B bf16 O[32][64] + 128 B f32 l[32]
#define NSLOT  2304          // 4 batches x 72 chunk-slots x 8 (wave,halfpass)

__device__ __forceinline__ float ex2(float x) { return __builtin_amdgcn_exp2f(x); }
__device__ __forceinline__ float bfbits2f(u16 u) {
    return __uint_as_float(((u32)u) << 16);
}
__device__ __forceinline__ u16 f2bf(float f) {
    return (u16)((__float_as_uint(f) + 0x8000u) >> 16);
}
__device__ __forceinline__ u32 pkbf(float a, float b) { // lo16=bf(a), hi16=bf(b)
    u32 xa = __float_as_uint(a) + 0x8000u;
    u32 xb = __float_as_uint(b) + 0x8000u;
    return __builtin_amdgcn_perm(xb, xa, 0x07060302);
}
// Deterministic per-wave dtype sniff (same answer in every wave/block).
__device__ __forceinline__ int sniff_bf16(const u32* x) {
    u32 w = x[threadIdx.x & 63];
    u32 lo = w & 0xffffu;
    u32 e  = (lo >> 7) & 0xffu;
    bool ok = (lo == 0u) || (e >= 96u && e <= 134u);
    u64 bal = __ballot(ok);
    return (__popcll(bal) >= 48) ? 1 : 0;
}
// chunk-slot prefix for qt256 (256-row q tiles, chunks of 8 k-tiles):
// nchunk(j) = (j>>1)+1; off(n) = sum_{j<n} nchunk(j) = h*(h-1+(n&1)) + n, h=n>>1.
// Total per batch (n=16): 72.
__device__ __forceinline__ int chunk_off(int n) {
    const int h = n >> 1;
    return h * (h - 1 + (n & 1)) + n;
}

// ---------------- W pre-conversion: fp32 -> bf16, ONCE ---------------------
__global__ __launch_bounds__(256) void wconv_kernel(
    const u32* __restrict__ xs,
    const void* __restrict__ wq, const void* __restrict__ wk,
    const void* __restrict__ wv, u16* __restrict__ wb)
{
    const int flag = sniff_bf16(xs);
    const int j = blockIdx.x * 256 + threadIdx.x;   // 0..18431
    const int e = j * 8;
    const int r = e / DIM;          // 0..191  ([wq;wk;wv] stacked)
    const int c = e - r * DIM;
    const void* src = (r < 64) ? wq : (r < 128) ? wk : wv;
    const long soff = (long)(r & 63) * DIM + c;
    if (flag) {
        *reinterpret_cast<short8*>(wb + (long)r * DIM + c) =
            *reinterpret_cast<const short8*>((const u16*)src + soff);
    } else {
        const float* p = (const float*)src + soff;
        float4 a = *reinterpret_cast<const float4*>(p);
        float4 d = *reinterpret_cast<const float4*>(p + 4);
        union { u32 u[4]; short8 s; } un;
        un.u[0] = pkbf(a.x, a.y); un.u[1] = pkbf(a.z, a.w);
        un.u[2] = pkbf(d.x, d.y); un.u[3] = pkbf(d.z, d.w);
        *reinterpret_cast<short8*>(wb + (long)r * DIM + c) = un.s;
    }
}

// ---------------- QKV projection: LDS-tiled GEMM (m97 shape) ----------------
__global__ __launch_bounds__(512, 4) void qkv_kernel(
    const void* __restrict__ x, const u16* __restrict__ wb,
    const int* __restrict__ mask,
    u16* __restrict__ qws, u16* __restrict__ kws, u16* __restrict__ vTws,
    u32* __restrict__ mb)
{
    const int t = threadIdx.x;
    const int l = t & 63;
    const int w = t >> 6;

    if (blockIdx.x >= 256) {            // ---- mask bit-pack ----
        const int base = (blockIdx.x - 256) * 8192 + w * 1024;
#pragma unroll
        for (int it = 0; it < 16; ++it) {
            const int idx = base + it * 64 + l;
            u64 bal = __ballot(mask[idx] != 0);
            if (l == 0)       mb[idx >> 5] = (u32)bal;
            else if (l == 32) mb[idx >> 5] = (u32)(bal >> 32);
        }
        return;
    }

    const int flag = sniff_bf16((const u32*)x);
    __shared__ __align__(16) u16 Xl[64 * 64];    // 8 KB,  slot r*64 + cc*8
    __shared__ __align__(16) u16 Wl[192 * 64];   // 24 KB, slot n*64 + cc*8
    __shared__ u16 Vt[64][66];                   // 8.4 KB transpose staging

    const int li = l & 15;
    const int g  = l >> 4;
    const int g4 = g * 4;
    const int strip = w & 3;            // 16-row strip
    const int nhalf = w >> 2;           // 96-col half
    const int m0 = blockIdx.x * 64;
    const int b  = m0 >> 12;

    auto ldbf = [&](const void* bp, long off) -> short8 {
        if (flag) return *reinterpret_cast<const short8*>((const u16*)bp + off);
        const float* p = (const float*)bp + off;
        float4 a = *reinterpret_cast<const float4*>(p);
        float4 c = *reinterpret_cast<const float4*>(p + 4);
        union { u32 u[4]; short8 s; } un;
        un.u[0] = pkbf(a.x, a.y); un.u[1] = pkbf(a.z, a.w);
        un.u[2] = pkbf(c.x, c.y); un.u[3] = pkbf(c.z, c.w);
        return un.s;
    };

    const int xr = t >> 3, xcc = t & 7, xc = xcc ^ (xr & 7);
    const long xsoff = (long)(m0 + xr) * DIM + xc * 8;
    long wboff[3]; int wdst[3];
#pragma unroll
    for (int j = 0; j < 3; ++j) {
        const int idx = j * 512 + t;
        const int r = idx >> 3, cc = idx & 7, c = cc ^ (r & 7);
        wboff[j] = (long)r * DIM + c * 8;     // r = 0..191 into stacked wb
        wdst[j]  = idx * 8;                   // u16 offset into Wl
    }

    const int am = strip * 16 + li;
    const int a0off = am * 64 + ((g       ^ (am & 7)) * 8);
    const int a1off = am * 64 + (((g | 4) ^ (am & 7)) * 8);
    int boff[12];
#pragma unroll
    for (int ns = 0; ns < 6; ++ns) {
        const int n = nhalf * 96 + ns * 16 + li;
        boff[2*ns]   = n * 64 + ((g       ^ (n & 7)) * 8);
        boff[2*ns+1] = n * 64 + (((g | 4) ^ (n & 7)) * 8);
    }

    f32x4 acc[6];
#pragma unroll
    for (int i = 0; i < 6; ++i) acc[i] = (f32x4){0.f, 0.f, 0.f, 0.f};

    short8 xs  = ldbf(x, xsoff);
    short8 ws0 = *reinterpret_cast<const short8*>(wb + wboff[0]);
    short8 ws1 = *reinterpret_cast<const short8*>(wb + wboff[1]);
    short8 ws2 = *reinterpret_cast<const short8*>(wb + wboff[2]);

    for (int kc = 0; kc < 12; ++kc) {
        __syncthreads();                 // previous K-step's LDS reads done
        *reinterpret_cast<short8*>(&Xl[t * 8])    = xs;
        *reinterpret_cast<short8*>(&Wl[wdst[0]])  = ws0;
        *reinterpret_cast<short8*>(&Wl[wdst[1]])  = ws1;
        *reinterpret_cast<short8*>(&Wl[wdst[2]])  = ws2;
        if (kc < 11) {                   // prefetch next staging tile
            const long o = (long)(kc + 1) * 64;
            xs  = ldbf(x, xsoff + o);
            ws0 = *reinterpret_cast<const short8*>(wb + wboff[0] + o);
            ws1 = *reinterpret_cast<const short8*>(wb + wboff[1] + o);
            ws2 = *reinterpret_cast<const short8*>(wb + wboff[2] + o);
        }
        __syncthreads();                 // staging visible
        short8 af0 = *reinterpret_cast<const short8*>(&Xl[a0off]);
        short8 af1 = *reinterpret_cast<const short8*>(&Xl[a1off]);
#pragma unroll
        for (int ns = 0; ns < 6; ++ns) {
            short8 b0 = *reinterpret_cast<const short8*>(&Wl[boff[2*ns]]);
            short8 b1 = *reinterpret_cast<const short8*>(&Wl[boff[2*ns+1]]);
            acc[ns] = __builtin_amdgcn_mfma_f32_16x16x32_bf16(af0, b0, acc[ns], 0, 0, 0);
            acc[ns] = __builtin_amdgcn_mfma_f32_16x16x32_bf16(af1, b1, acc[ns], 0, 0, 0);
        }
    }

#pragma unroll
    for (int ns = 0; ns < 6; ++ns) {
        const int n = nhalf * 96 + ns * 16 + li;
#pragma unroll
        for (int r = 0; r < 4; ++r) {
            const int rowl = strip * 16 + g4 + r;
            u16 bv = f2bf(acc[ns][r]);
            if (n < 64)        qws[(long)(m0 + rowl) * HD + n]        = bv;
            else if (n < 128)  kws[(long)(m0 + rowl) * HD + (n - 64)] = bv;
            else               Vt[rowl][n - 128]                      = bv;
        }
    }
    __syncthreads();
    {
        const int d  = t >> 3;   // 0..63
        const int mg = t & 7;    // 0..7
        union { u16 h[8]; short8 s; } u;
#pragma unroll
        for (int i = 0; i < 8; ++i) u.h[i] = Vt[mg * 8 + i][d];
        u16* dst = vTws + ((long)(b * 64 + d)) * VSTRIDE + (m0 & (SEQ - 1)) + mg * 8;
        *reinterpret_cast<short8*>(dst) = u.s;
    }
}

// ---------------- Flash attention: 64 q-rows per wave ----------------
// Empirical law (r0-r6): attn time tracks WAVE-ITERATION COUNT, insensitive
// to traffic (4x, r6), parallelism (r4), pipeline depth (r2-r5). The only
// lever that moved it was widening the per-wave q-tile (r0->r1: 16->32 rows,
// -38%). This round: 64 q-rows/wave (4x 16-row MFMA subtiles A..D sharing
// the same K/V regs) -> 8704 iterations (was 16640).
// Block = 256 q-rows (qt256), 4 waves. Convoy s_barrier keeps waves on the
// same k-tile (L1 sharing). Single Ps buffer: A-frags are register-read
// BEFORE the next sphase overwrites them; within-wave DS ops are in-order.
// __launch_bounds__(256,2): ~220 live VGPRs need the 256 cap (r5's spill was
// at cap 170). Epilogue = r6's proven 32-row staging, run twice (p=0,1).
// NO runtime selection between register arrays anywhere (r2/r3 scratch trap).
__global__ __launch_bounds__(256, 2) void attn_kernel(
    const u32* __restrict__ xs,
    const u16* __restrict__ qw, const u16* __restrict__ kw,
    const u16* __restrict__ vTw, const u32* __restrict__ maskbits,
    char* __restrict__ part, void* __restrict__ out)
{
    __shared__ __align__(16) u16 Ps[4][4][16][72];   // 36.9 KB, per-wave regions

    const int flag = sniff_bf16(xs);
    const int t  = threadIdx.x;
    const int l  = t & 63;
    const int w  = t >> 6;
    const int li = l & 15;
    const int g  = l >> 4;
    const int g4 = g * 4;

    // XCD-affine decode: b = (bid%8)>>1; s = per-batch task 0..71, heavy first.
    const int bid = blockIdx.x;          // grid = 288
    const int b   = (bid & 7) >> 1;
    const int s   = (bid >> 3) * 2 + (bid & 1);
    int qt256, c;
    if      (s < 16) { qt256 = 15 - (s >> 3);              c = s & 7;  }  // 8 chunks
    else if (s < 30) { const int u = s - 16; qt256 = 13 - u / 7; c = u % 7; }
    else if (s < 42) { const int u = s - 30; qt256 = 11 - u / 6; c = u % 6; }
    else if (s < 52) { const int u = s - 42; qt256 = 9  - u / 5; c = u % 5; }
    else if (s < 60) { const int u = s - 52; qt256 = 7  - (u >> 2); c = u & 3; }
    else if (s < 66) { const int u = s - 60; qt256 = 5  - u / 3; c = u % 3; }
    else if (s < 70) { const int u = s - 66; qt256 = 3  - (u >> 1); c = u & 1; }
    else             { qt256 = 1 - (s - 70);               c = 0;  }      // 1 chunk
    const int nkt    = 4 * qt256 + 4;
    const int ktBeg  = c * 8;
    const int ktEnd  = min(ktBeg + 8, nkt);
    const int ntile  = ktEnd - ktBeg;            // 4..8, uniform across waves
    const bool single = (qt256 < 2);             // 1 chunk -> direct out write
    const int q0     = qt256 * 256 + w * 64;     // this wave's 64 q rows

    const u16* qrow = qw + ((long)(b * SEQ + q0 + li)) * HD + g * 8;
    short8 qf0 = *reinterpret_cast<const short8*>(qrow);
    short8 qf1 = *reinterpret_cast<const short8*>(qrow + 32);
    short8 qf2 = *reinterpret_cast<const short8*>(qrow + 16 * HD);
    short8 qf3 = *reinterpret_cast<const short8*>(qrow + 16 * HD + 32);
    short8 qf4 = *reinterpret_cast<const short8*>(qrow + 32 * HD);
    short8 qf5 = *reinterpret_cast<const short8*>(qrow + 32 * HD + 32);
    short8 qf6 = *reinterpret_cast<const short8*>(qrow + 48 * HD);
    short8 qf7 = *reinterpret_cast<const short8*>(qrow + 48 * HD + 32);

    short8 ones;
#pragma unroll
    for (int i = 0; i < 8; ++i) ones[i] = (short)0x3F80;  // bf16 1.0

    f32x4 O[16];
#pragma unroll
    for (int i = 0; i < 16; ++i) O[i] = (f32x4){0.f, 0.f, 0.f, 0.f};
    f32x4 l4A = (f32x4){0.f, 0.f, 0.f, 0.f};
    f32x4 l4B = (f32x4){0.f, 0.f, 0.f, 0.f};
    f32x4 l4C = (f32x4){0.f, 0.f, 0.f, 0.f};
    f32x4 l4D = (f32x4){0.f, 0.f, 0.f, 0.f};
    const int qgA = q0 + li;
    const int qgB = q0 + 16 + li;
    const int qgC = q0 + 32 + li;
    const int qgD = q0 + 48 + li;
    const f32x4 z4 = (f32x4){0.f, 0.f, 0.f, 0.f};

    const u16* kbase = kw  + ((long)(b * SEQ) + li) * HD + g * 8;
    const u16* vbase = vTw + ((long)(b * 64)  + li) * VSTRIDE + g * 8;
    const int tLast = ntile - 1;

    short8 ka[8];
    short8 vf[8];
    auto kload = [&](int i) {                     // clamped prefetch, tile idx
        const int tt = (i > tLast) ? tLast : i;
        const u16* kp = kbase + (long)((ktBeg + tt) * 64) * HD;
#pragma unroll
        for (int sub = 0; sub < 4; ++sub) {
            ka[2*sub]   = *reinterpret_cast<const short8*>(kp + sub * 16 * HD);
            ka[2*sub+1] = *reinterpret_cast<const short8*>(kp + sub * 16 * HD + 32);
        }
    };
    auto vfload = [&](int i) {
        const int k0 = (ktBeg + i) * 64;
#pragma unroll
        for (int ds = 0; ds < 4; ++ds) {
            const u16* vr = vbase + (long)(ds * 16) * VSTRIDE + k0;
            vf[2*ds]   = *reinterpret_cast<const short8*>(vr);
            vf[2*ds+1] = *reinterpret_cast<const short8*>(vr + 32);
        }
    };
    auto sphase = [&](int i) {            // S^T + softmax -> Ps[w][qs], 4 subtiles
        const int k0 = (ktBeg + i) * 64;
        const u32 mb0 = maskbits[b * 128 + (k0 >> 5)];
        const u32 mb1 = maskbits[b * 128 + (k0 >> 5) + 1];
#pragma unroll
        for (int sub = 0; sub < 4; ++sub) {
            const u32 word = (sub & 2) ? mb1 : mb0;
            const int klb = k0 + sub * 16 + g4;
            const int sh  = (sub & 1) * 16 + g4;
            // subtile A
            {
                f32x4 a = __builtin_amdgcn_mfma_f32_16x16x32_bf16(ka[2*sub],   qf0, z4, 0, 0, 0);
                a       = __builtin_amdgcn_mfma_f32_16x16x32_bf16(ka[2*sub+1], qf1, a,  0, 0, 0);
                float p[4];
#pragma unroll
                for (int r = 0; r < 4; ++r) {
                    const bool keep = ((klb + r) <= qgA) && (((word >> (sh + r)) & 1u) != 0u);
                    p[r] = ex2(fmaf(a[r], SSCALE, keep ? CSHIFT : NEGBIG));
                }
                *reinterpret_cast<uint2*>(&Ps[w][0][li][sub * 16 + g4]) =
                    make_uint2(pkbf(p[0], p[1]), pkbf(p[2], p[3]));
            }
            // subtile B
            {
                f32x4 a = __builtin_amdgcn_mfma_f32_16x16x32_bf16(ka[2*sub],   qf2, z4, 0, 0, 0);
                a       = __builtin_amdgcn_mfma_f32_16x16x32_bf16(ka[2*sub+1], qf3, a,  0, 0, 0);
                float p[4];
#pragma unroll
                for (int r = 0; r < 4; ++r) {
                    const bool keep = ((klb + r) <= qgB) && (((word >> (sh + r)) & 1u) != 0u);
                    p[r] = ex2(fmaf(a[r], SSCALE, keep ? CSHIFT : NEGBIG));
                }
                *reinterpret_cast<uint2*>(&Ps[w][1][li][sub * 16 + g4]) =
                    make_uint2(pkbf(p[0], p[1]), pkbf(p[2], p[3]));
            }
            // subtile C
            {
                f32x4 a = __builtin_amdgcn_mfma_f32_16x16x32_bf16(ka[2*sub],   qf4, z4, 0, 0, 0);
                a       = __builtin_amdgcn_mfma_f32_16x16x32_bf16(ka[2*sub+1], qf5, a,  0, 0, 0);
                float p[4];
#pragma unroll
                for (int r = 0; r < 4; ++r) {
                    const bool keep = ((klb + r) <= qgC) && (((word >> (sh + r)) & 1u) != 0u);
                    p[r] = ex2(fmaf(a[r], SSCALE, keep ? CSHIFT : NEGBIG));
                }
                *reinterpret_cast<uint2*>(&Ps[w][2][li][sub * 16 + g4]) =
                    make_uint2(pkbf(p[0], p[1]), pkbf(p[2], p[3]));
            }
            // subtile D
            {
                f32x4 a = __builtin_amdgcn_mfma_f32_16x16x32_bf16(ka[2*sub],   qf6, z4, 0, 0, 0);
                a       = __builtin_amdgcn_mfma_f32_16x16x32_bf16(ka[2*sub+1], qf7, a,  0, 0, 0);
                float p[4];
#pragma unroll
                for (int r = 0; r < 4; ++r) {
                    const bool keep = ((klb + r) <= qgD) && (((word >> (sh + r)) & 1u) != 0u);
                    p[r] = ex2(fmaf(a[r], SSCALE, keep ? CSHIFT : NEGBIG));
                }
                *reinterpret_cast<uint2*>(&Ps[w][3][li][sub * 16 + g4]) =
                    make_uint2(pkbf(p[0], p[1]), pkbf(p[2], p[3]));
            }
        }
    };

    kload(0);
    sphase(0);
    kload(1);
    for (int i = 0; i < ntile; ++i) {
        __builtin_amdgcn_s_barrier();   // convoy: keep 4 waves on same tile
        vfload(i);
        short8 A1A = *reinterpret_cast<const short8*>(&Ps[w][0][li][g * 8]);
        short8 A2A = *reinterpret_cast<const short8*>(&Ps[w][0][li][32 + g * 8]);
        short8 A1B = *reinterpret_cast<const short8*>(&Ps[w][1][li][g * 8]);
        short8 A2B = *reinterpret_cast<const short8*>(&Ps[w][1][li][32 + g * 8]);
        short8 A1C = *reinterpret_cast<const short8*>(&Ps[w][2][li][g * 8]);
        short8 A2C = *reinterpret_cast<const short8*>(&Ps[w][2][li][32 + g * 8]);
        short8 A1D = *reinterpret_cast<const short8*>(&Ps[w][3][li][g * 8]);
        short8 A2D = *reinterpret_cast<const short8*>(&Ps[w][3][li][32 + g * 8]);
        if (i + 1 < ntile) {
            sphase(i + 1);               // overwrites Ps AFTER the reg-reads above
            kload(i + 2);                // refill single K buffer (clamped)
        }
        f32x4 lt;
        lt = __builtin_amdgcn_mfma_f32_16x16x32_bf16(A1A, ones, z4, 0, 0, 0);
        lt = __builtin_amdgcn_mfma_f32_16x16x32_bf16(A2A, ones, lt, 0, 0, 0);
#pragma unroll
        for (int r = 0; r < 4; ++r) l4A[r] += lt[r];
        lt = __builtin_amdgcn_mfma_f32_16x16x32_bf16(A1B, ones, z4, 0, 0, 0);
        lt = __builtin_amdgcn_mfma_f32_16x16x32_bf16(A2B, ones, lt, 0, 0, 0);
#pragma unroll
        for (int r = 0; r < 4; ++r) l4B[r] += lt[r];
        lt = __builtin_amdgcn_mfma_f32_16x16x32_bf16(A1C, ones, z4, 0, 0, 0);
        lt = __builtin_amdgcn_mfma_f32_16x16x32_bf16(A2C, ones, lt, 0, 0, 0);
#pragma unroll
        for (int r = 0; r < 4; ++r) l4C[r] += lt[r];
        lt = __builtin_amdgcn_mfma_f32_16x16x32_bf16(A1D, ones, z4, 0, 0, 0);
        lt = __builtin_amdgcn_mfma_f32_16x16x32_bf16(A2D, ones, lt, 0, 0, 0);
#pragma unroll
        for (int r = 0; r < 4; ++r) l4D[r] += lt[r];
#pragma unroll
        for (int ds = 0; ds < 4; ++ds) {
            O[ds]      = __builtin_amdgcn_mfma_f32_16x16x32_bf16(A1A, vf[2*ds],   O[ds],      0, 0, 0);
            O[ds]      = __builtin_amdgcn_mfma_f32_16x16x32_bf16(A2A, vf[2*ds+1], O[ds],      0, 0, 0);
            O[4 + ds]  = __builtin_amdgcn_mfma_f32_16x16x32_bf16(A1B, vf[2*ds],   O[4 + ds],  0, 0, 0);
            O[4 + ds]  = __builtin_amdgcn_mfma_f32_16x16x32_bf16(A2B, vf[2*ds+1], O[4 + ds],  0, 0, 0);
            O[8 + ds]  = __builtin_amdgcn_mfma_f32_16x16x32_bf16(A1C, vf[2*ds],   O[8 + ds],  0, 0, 0);
            O[8 + ds]  = __builtin_amdgcn_mfma_f32_16x16x32_bf16(A2C, vf[2*ds+1], O[8 + ds],  0, 0, 0);
            O[12 + ds] = __builtin_amdgcn_mfma_f32_16x16x32_bf16(A1D, vf[2*ds],   O[12 + ds], 0, 0, 0);
            O[12 + ds] = __builtin_amdgcn_mfma_f32_16x16x32_bf16(A2D, vf[2*ds+1], O[12 + ds], 0, 0, 0);
        }
    }

    // ---- per-wave epilogue: two 32-row passes through this wave's Ps region ----
    // Of[32][stride 66] f32 (8448 B) + Lf[32] f32 fit in the 9216 B region.
    {
        float* Of = reinterpret_cast<float*>(&Ps[w][0][0][0]);
        float* Lf = Of + 2112;
        const int r32 = l >> 1;          // 0..31: output row within pass
        const int h   = l & 1;           // column half (32 cols)
#pragma unroll
        for (int p = 0; p < 2; ++p) {
#pragma unroll
            for (int tile = 0; tile < 2; ++tile)
#pragma unroll
                for (int ds = 0; ds < 4; ++ds)
#pragma unroll
                    for (int r = 0; r < 4; ++r)
                        Of[(tile * 16 + g4 + r) * 66 + ds * 16 + li] =
                            O[(p * 2 + tile) * 4 + ds][r];
            if (li == 0) {
#pragma unroll
                for (int r = 0; r < 4; ++r) {
                    Lf[g4 + r]      = p ? l4C[r] : l4A[r];
                    Lf[16 + g4 + r] = p ? l4D[r] : l4B[r];
                }
            }
            float v[32];
#pragma unroll
            for (int j = 0; j < 8; ++j) {
                float4 f = *reinterpret_cast<const float4*>(&Of[r32 * 66 + h * 32 + j * 4]);
                v[4*j] = f.x; v[4*j+1] = f.y; v[4*j+2] = f.z; v[4*j+3] = f.w;
            }
            if (single) {
                const float L = Lf[r32];
                const float rl = (L > 0.f) ? 1.f / L : 0.f;
#pragma unroll
                for (int j = 0; j < 32; ++j) v[j] *= rl;
                const long row = (long)(b * SEQ + q0 + p * 32 + r32);
                if (flag) {
                    u16* dst = (u16*)out + row * HD + h * 32;
#pragma unroll
                    for (int jj = 0; jj < 4; ++jj) {
                        uint4 st = make_uint4(pkbf(v[8*jj],   v[8*jj+1]), pkbf(v[8*jj+2], v[8*jj+3]),
                                              pkbf(v[8*jj+4], v[8*jj+5]), pkbf(v[8*jj+6], v[8*jj+7]));
                        *reinterpret_cast<uint4*>(dst + jj * 8) = st;
                    }
                } else {
                    float* dst = (float*)out + row * HD + h * 32;
#pragma unroll
                    for (int jj = 0; jj < 8; ++jj)
                        *reinterpret_cast<float4*>(dst + jj * 4) =
                            make_float4(v[4*jj], v[4*jj+1], v[4*jj+2], v[4*jj+3]);
                }
            } else {
                const int slotIdx = ((b * 72 + chunk_off(qt256) + c) * 8 + w * 2 + p);
                char* slot = part + (long)slotIdx * PSLOTB;
                u16* dst = (u16*)slot + r32 * 64 + h * 32;
#pragma unroll
                for (int jj = 0; jj < 4; ++jj) {
                    uint4 st = make_uint4(pkbf(v[8*jj],   v[8*jj+1]), pkbf(v[8*jj+2], v[8*jj+3]),
                                          pkbf(v[8*jj+4], v[8*jj+5]), pkbf(v[8*jj+6], v[8*jj+7]));
                    *reinterpret_cast<uint4*>(dst + jj * 8) = st;
                }
                if (l < 32)
                    *reinterpret_cast<float*>(slot + 4096 + l * 4) = Lf[l];
            }
        }
    }
}

// ---------------- merge split-K partials (qt256 >= 2): plain sum ----------
__global__ __launch_bounds__(256) void merge_kernel(
    const u32* __restrict__ xs, const char* __restrict__ part,
    void* __restrict__ out)
{
    const int flag = sniff_bf16(xs);
    const int bid = blockIdx.x;         // 448
    const int b = bid & 3;
    const int u = bid >> 2;             // 0..111
    const int qt256 = 2 + u / 8;        // 2..15
    const int v8 = u % 8;
    const int w = v8 >> 1;              // wave 0..3
    const int p = v8 & 1;               // half-pass 0..1
    const int nc = (qt256 >> 1) + 1;    // 2..8 chunks
    const int t  = threadIdx.x;
    const int qq = t >> 3;              // 0..31
    const int dd = (t & 7) * 8;         // 0..56
    const char* s0 = part +
        ((long)((b * 72 + chunk_off(qt256)) * 8 + w * 2 + p)) * PSLOTB;
    float L = 0.f;
    float a8[8];
#pragma unroll
    for (int j = 0; j < 8; ++j) a8[j] = 0.f;
    for (int c = 0; c < nc; ++c) {
        const char* sc = s0 + (long)c * 8 * PSLOTB;   // c-stride = 8 slots
        L += *reinterpret_cast<const float*>(sc + 4096 + qq * 4);
        ushort4 x0 = *reinterpret_cast<const ushort4*>((const u16*)sc + qq * 64 + dd);
        ushort4 x1 = *reinterpret_cast<const ushort4*>((const u16*)sc + qq * 64 + dd + 4);
        a8[0] += bfbits2f(x0.x); a8[1] += bfbits2f(x0.y);
        a8[2] += bfbits2f(x0.z); a8[3] += bfbits2f(x0.w);
        a8[4] += bfbits2f(x1.x); a8[5] += bfbits2f(x1.y);
        a8[6] += bfbits2f(x1.z); a8[7] += bfbits2f(x1.w);
    }
    const float rl = (L > 0.f) ? 1.f / L : 0.f;
#pragma unroll
    for (int j = 0; j < 8; ++j) a8[j] *= rl;
    const long row = (long)(b * SEQ + qt256 * 256 + w * 64 + p * 32 + qq);
    if (flag) {
        uint4 st = make_uint4(pkbf(a8[0], a8[1]), pkbf(a8[2], a8[3]),
                              pkbf(a8[4], a8[5]), pkbf(a8[6], a8[7]));
        *reinterpret_cast<uint4*>((u16*)out + row * HD + dd) = st;
    } else {
        *reinterpret_cast<float4*>((float*)out + row * HD + dd) =
            make_float4(a8[0], a8[1], a8[2], a8[3]);
        *reinterpret_cast<float4*>((float*)out + row * HD + dd + 4) =
            make_float4(a8[4], a8[5], a8[6], a8[7]);
    }
}

extern "C" void kernel_launch(void* const* d_in, const int* in_sizes, int n_in,
                              void* d_out, int out_size, void* d_ws, size_t ws_size,
                              hipStream_t stream) {
    const void* x   = d_in[0];
    const int* mask = (const int*)d_in[1];
    const void* wq  = d_in[2];
    const void* wk  = d_in[3];
    const void* wv  = d_in[4];
    const u32* xs   = (const u32*)x;

    u16* q    = (u16*)d_ws;                          // 2 MB
    u16* k    = q  + (long)NROW * HD;                // 2 MB
    u16* vT   = k  + (long)NROW * HD;                // 2.16 MB
    u32* mb   = (u32*)(vT + (long)BATCH * 64 * VSTRIDE);  // 2 KB
    char* part = (char*)(mb + 512);                  // 2304 slots = 9.73 MB
    u16* wb   = (u16*)(part + (long)NSLOT * PSLOTB); // 288 KB bf16 W

    wconv_kernel<<<72, 256, 0, stream>>>(xs, wq, wk, wv, wb);
    qkv_kernel  <<<258, 512, 0, stream>>>(x, wb, mask, q, k, vT, mb);
    attn_kernel <<<288, 256, 0, stream>>>(xs, q, k, vT, mb, part, d_out);
    merge_kernel<<<448, 256, 0, stream>>>(xs, part, d_out);
}

// Round 8
// 139.691 us; speedup vs baseline: 1.2282x; 1.0470x over previous
//
#include <hip/hip_runtime.h>
#include <hip/hip_bf16.h>

typedef unsigned int u32;
typedef unsigned short u16;
typedef unsigned long long u64;
typedef __attribute__((ext_vector_type(8))) short short8;
typedef __attribute__((ext_vector_type(4))) float f32x4;

#define BATCH 4
#define SEQ   4096
#define DIM   768
#define HD    64
#define NROW  (BATCH*SEQ)   // 16384
#define LOG2E 1.44269504088896f
#define SSCALE (0.125f * LOG2E)
#define CSHIFT (-32.0f)      // fixed exp2-domain shift (softmax shift-invariant)
#define NEGBIG (-1.0e30f)
#define PSLOTB 4224          // partial slot: 4096 B bf16 O[32][64] + 128 B f32 l[32]
#define NSLOT  2304          // 4 batches x 72 chunk-slots x 8 (wave,halfpass)

__device__ __forceinline__ float ex2(float x) { return __builtin_amdgcn_exp2f(x); }
__device__ __forceinline__ float bfbits2f(u16 u) {
    return __uint_as_float(((u32)u) << 16);
}
__device__ __forceinline__ u16 f2bf(float f) {
    return (u16)((__float_as_uint(f) + 0x8000u) >> 16);
}
__device__ __forceinline__ u32 pkbf(float a, float b) { // lo16=bf(a), hi16=bf(b)
    u32 xa = __float_as_uint(a) + 0x8000u;
    u32 xb = __float_as_uint(b) + 0x8000u;
    return __builtin_amdgcn_perm(xb, xa, 0x07060302);
}
// Deterministic per-wave dtype sniff (same answer in every wave/block).
__device__ __forceinline__ int sniff_bf16(const u32* x) {
    u32 w = x[threadIdx.x & 63];
    u32 lo = w & 0xffffu;
    u32 e  = (lo >> 7) & 0xffu;
    bool ok = (lo == 0u) || (e >= 96u && e <= 134u);
    u64 bal = __ballot(ok);
    return (__popcll(bal) >= 48) ? 1 : 0;
}
// chunk-slot prefix for qt256 (256-row q tiles, chunks of 8 k-tiles):
// nchunk(j) = (j>>1)+1; off(n) = h*(h-1+(n&1)) + n, h=n>>1. Total 72/batch.
__device__ __forceinline__ int chunk_off(int n) {
    const int h = n >> 1;
    return h * (h - 1 + (n & 1)) + n;
}

// ---------------- W pre-conversion: fp32 -> bf16, ONCE ---------------------
__global__ __launch_bounds__(256) void wconv_kernel(
    const u32* __restrict__ xs,
    const void* __restrict__ wq, const void* __restrict__ wk,
    const void* __restrict__ wv, u16* __restrict__ wb)
{
    const int flag = sniff_bf16(xs);
    const int j = blockIdx.x * 256 + threadIdx.x;   // 0..18431
    const int e = j * 8;
    const int r = e / DIM;          // 0..191  ([wq;wk;wv] stacked)
    const int c = e - r * DIM;
    const void* src = (r < 64) ? wq : (r < 128) ? wk : wv;
    const long soff = (long)(r & 63) * DIM + c;
    if (flag) {
        *reinterpret_cast<short8*>(wb + (long)r * DIM + c) =
            *reinterpret_cast<const short8*>((const u16*)src + soff);
    } else {
        const float* p = (const float*)src + soff;
        float4 a = *reinterpret_cast<const float4*>(p);
        float4 d = *reinterpret_cast<const float4*>(p + 4);
        union { u32 u[4]; short8 s; } un;
        un.u[0] = pkbf(a.x, a.y); un.u[1] = pkbf(a.z, a.w);
        un.u[2] = pkbf(d.x, d.y); un.u[3] = pkbf(d.z, d.w);
        *reinterpret_cast<short8*>(wb + (long)r * DIM + c) = un.s;
    }
}

// ---------------- QKV projection: LDS-tiled GEMM (m97 shape) ----------------
// K and V are written in MFMA-FRAGMENT-MAJOR TILE LAYOUT: per 64x64 tile,
// element for (load-instruction m, lane l, elem e) sits at
// tile*4096 + m*512 + l*8 + e (u16). attn's kload/vfload then become 8 fully
// coalesced 1KB loads per tile (64 lanes x 16B contiguous) instead of 16
// scattered-row transactions per instruction — the r0-r7 invariant
// (~2.6us per block-iteration regardless of traffic/TLP/pipelining) is
// attributed to scattered line-request processing in the TA/L1 path.
//   K: row=16s+(l&15), col=32h+8*(l>>4)+e  <->  m=2s+h
//   V: dim d=16*(m>>1)+(l&15), seqpos kk=32*(m&1)+8*(l>>4)+e
__global__ __launch_bounds__(512, 4) void qkv_kernel(
    const void* __restrict__ x, const u16* __restrict__ wb,
    const int* __restrict__ mask,
    u16* __restrict__ qws, u16* __restrict__ kws, u16* __restrict__ vpws,
    u32* __restrict__ mb)
{
    const int t = threadIdx.x;
    const int l = t & 63;
    const int w = t >> 6;

    if (blockIdx.x >= 256) {            // ---- mask bit-pack ----
        const int base = (blockIdx.x - 256) * 8192 + w * 1024;
#pragma unroll
        for (int it = 0; it < 16; ++it) {
            const int idx = base + it * 64 + l;
            u64 bal = __ballot(mask[idx] != 0);
            if (l == 0)       mb[idx >> 5] = (u32)bal;
            else if (l == 32) mb[idx >> 5] = (u32)(bal >> 32);
        }
        return;
    }

    const int flag = sniff_bf16((const u32*)x);
    __shared__ __align__(16) u16 Xl[64 * 64];    // 8 KB,  slot r*64 + cc*8
    __shared__ __align__(16) u16 Wl[192 * 64];   // 24 KB, slot n*64 + cc*8
    __shared__ u16 Vt[64][66];                   // 8.4 KB transpose staging

    const int li = l & 15;
    const int g  = l >> 4;
    const int g4 = g * 4;
    const int strip = w & 3;            // 16-row strip
    const int nhalf = w >> 2;           // 96-col half
    const int m0 = blockIdx.x * 64;
    const int b  = m0 >> 12;

    auto ldbf = [&](const void* bp, long off) -> short8 {
        if (flag) return *reinterpret_cast<const short8*>((const u16*)bp + off);
        const float* p = (const float*)bp + off;
        float4 a = *reinterpret_cast<const float4*>(p);
        float4 c = *reinterpret_cast<const float4*>(p + 4);
        union { u32 u[4]; short8 s; } un;
        un.u[0] = pkbf(a.x, a.y); un.u[1] = pkbf(a.z, a.w);
        un.u[2] = pkbf(c.x, c.y); un.u[3] = pkbf(c.z, c.w);
        return un.s;
    };

    const int xr = t >> 3, xcc = t & 7, xc = xcc ^ (xr & 7);
    const long xsoff = (long)(m0 + xr) * DIM + xc * 8;
    long wboff[3]; int wdst[3];
#pragma unroll
    for (int j = 0; j < 3; ++j) {
        const int idx = j * 512 + t;
        const int r = idx >> 3, cc = idx & 7, c = cc ^ (r & 7);
        wboff[j] = (long)r * DIM + c * 8;     // r = 0..191 into stacked wb
        wdst[j]  = idx * 8;                   // u16 offset into Wl
    }

    const int am = strip * 16 + li;
    const int a0off = am * 64 + ((g       ^ (am & 7)) * 8);
    const int a1off = am * 64 + (((g | 4) ^ (am & 7)) * 8);
    int boff[12];
#pragma unroll
    for (int ns = 0; ns < 6; ++ns) {
        const int n = nhalf * 96 + ns * 16 + li;
        boff[2*ns]   = n * 64 + ((g       ^ (n & 7)) * 8);
        boff[2*ns+1] = n * 64 + (((g | 4) ^ (n & 7)) * 8);
    }

    f32x4 acc[6];
#pragma unroll
    for (int i = 0; i < 6; ++i) acc[i] = (f32x4){0.f, 0.f, 0.f, 0.f};

    short8 xs  = ldbf(x, xsoff);
    short8 ws0 = *reinterpret_cast<const short8*>(wb + wboff[0]);
    short8 ws1 = *reinterpret_cast<const short8*>(wb + wboff[1]);
    short8 ws2 = *reinterpret_cast<const short8*>(wb + wboff[2]);

    for (int kc = 0; kc < 12; ++kc) {
        __syncthreads();                 // previous K-step's LDS reads done
        *reinterpret_cast<short8*>(&Xl[t * 8])    = xs;
        *reinterpret_cast<short8*>(&Wl[wdst[0]])  = ws0;
        *reinterpret_cast<short8*>(&Wl[wdst[1]])  = ws1;
        *reinterpret_cast<short8*>(&Wl[wdst[2]])  = ws2;
        if (kc < 11) {                   // prefetch next staging tile
            const long o = (long)(kc + 1) * 64;
            xs  = ldbf(x, xsoff + o);
            ws0 = *reinterpret_cast<const short8*>(wb + wboff[0] + o);
            ws1 = *reinterpret_cast<const short8*>(wb + wboff[1] + o);
            ws2 = *reinterpret_cast<const short8*>(wb + wboff[2] + o);
        }
        __syncthreads();                 // staging visible
        short8 af0 = *reinterpret_cast<const short8*>(&Xl[a0off]);
        short8 af1 = *reinterpret_cast<const short8*>(&Xl[a1off]);
#pragma unroll
        for (int ns = 0; ns < 6; ++ns) {
            short8 b0 = *reinterpret_cast<const short8*>(&Wl[boff[2*ns]]);
            short8 b1 = *reinterpret_cast<const short8*>(&Wl[boff[2*ns+1]]);
            acc[ns] = __builtin_amdgcn_mfma_f32_16x16x32_bf16(af0, b0, acc[ns], 0, 0, 0);
            acc[ns] = __builtin_amdgcn_mfma_f32_16x16x32_bf16(af1, b1, acc[ns], 0, 0, 0);
        }
    }

    // epilogue: q row-major; K fragment-major tile layout; V via LDS transpose
#pragma unroll
    for (int ns = 0; ns < 6; ++ns) {
        const int n = nhalf * 96 + ns * 16 + li;
#pragma unroll
        for (int r = 0; r < 4; ++r) {
            const int rowl = strip * 16 + g4 + r;
            u16 bv = f2bf(acc[ns][r]);
            if (n < 64) {
                qws[(long)(m0 + rowl) * HD + n] = bv;
            } else if (n < 128) {
                const int col = n - 64;                  // 0..63
                const int j   = 2 * strip + (col >> 5);  // m index
                const int gg  = (col >> 3) & 3;
                const int e   = col & 7;
                kws[(long)blockIdx.x * 4096 + j * 512 + (gg * 16 + (g4 + r)) * 8 + e] = bv;
            } else {
                Vt[rowl][n - 128] = bv;
            }
        }
    }
    __syncthreads();
    // V out in fragment-major layout: thread (d, mg) holds 8 consecutive kk
    // = mg*8..mg*8+7 for dim d -> contiguous short8 at (m, l) slot.
    {
        const int d  = t >> 3;   // 0..63
        const int mg = t & 7;    // 0..7
        union { u16 h[8]; short8 s; } u;
#pragma unroll
        for (int i = 0; i < 8; ++i) u.h[i] = Vt[mg * 8 + i][d];
        const int m  = 2 * (d >> 4) + (mg >> 2);
        const int lq = (mg & 3) * 16 + (d & 15);
        u16* dst = vpws + (long)blockIdx.x * 4096 + m * 512 + lq * 8;
        *reinterpret_cast<short8*>(dst) = u.s;
    }
}

// ---------------- Flash attention: 64 q-rows per wave, coalesced K/V ------
// Structure identical to round 7 (64 q-rows/wave, 4-wave convoy, single Ps
// buffer, single-ka pipeline, heavy-first <=8-k-tile chunks, XCD-affine).
// ONLY change: kload/vfload read the fragment-major tile layout — 8 fully
// coalesced 1KB loads per tile instead of 16 scattered-row transactions.
__global__ __launch_bounds__(256, 2) void attn_kernel(
    const u32* __restrict__ xs,
    const u16* __restrict__ qw, const u16* __restrict__ kw,
    const u16* __restrict__ vpw, const u32* __restrict__ maskbits,
    char* __restrict__ part, void* __restrict__ out)
{
    __shared__ __align__(16) u16 Ps[4][4][16][72];   // 36.9 KB, per-wave regions

    const int flag = sniff_bf16(xs);
    const int t  = threadIdx.x;
    const int l  = t & 63;
    const int w  = t >> 6;
    const int li = l & 15;
    const int g  = l >> 4;
    const int g4 = g * 4;

    // XCD-affine decode: b = (bid%8)>>1; s = per-batch task 0..71, heavy first.
    const int bid = blockIdx.x;          // grid = 288
    const int b   = (bid & 7) >> 1;
    const int s   = (bid >> 3) * 2 + (bid & 1);
    int qt256, c;
    if      (s < 16) { qt256 = 15 - (s >> 3);              c = s & 7;  }  // 8 chunks
    else if (s < 30) { const int u = s - 16; qt256 = 13 - u / 7; c = u % 7; }
    else if (s < 42) { const int u = s - 30; qt256 = 11 - u / 6; c = u % 6; }
    else if (s < 52) { const int u = s - 42; qt256 = 9  - u / 5; c = u % 5; }
    else if (s < 60) { const int u = s - 52; qt256 = 7  - (u >> 2); c = u & 3; }
    else if (s < 66) { const int u = s - 60; qt256 = 5  - u / 3; c = u % 3; }
    else if (s < 70) { const int u = s - 66; qt256 = 3  - (u >> 1); c = u & 1; }
    else             { qt256 = 1 - (s - 70);               c = 0;  }      // 1 chunk
    const int nkt    = 4 * qt256 + 4;
    const int ktBeg  = c * 8;
    const int ktEnd  = min(ktBeg + 8, nkt);
    const int ntile  = ktEnd - ktBeg;            // 4..8, uniform across waves
    const bool single = (qt256 < 2);             // 1 chunk -> direct out write
    const int q0     = qt256 * 256 + w * 64;     // this wave's 64 q rows

    const u16* qrow = qw + ((long)(b * SEQ + q0 + li)) * HD + g * 8;
    short8 qf0 = *reinterpret_cast<const short8*>(qrow);
    short8 qf1 = *reinterpret_cast<const short8*>(qrow + 32);
    short8 qf2 = *reinterpret_cast<const short8*>(qrow + 16 * HD);
    short8 qf3 = *reinterpret_cast<const short8*>(qrow + 16 * HD + 32);
    short8 qf4 = *reinterpret_cast<const short8*>(qrow + 32 * HD);
    short8 qf5 = *reinterpret_cast<const short8*>(qrow + 32 * HD + 32);
    short8 qf6 = *reinterpret_cast<const short8*>(qrow + 48 * HD);
    short8 qf7 = *reinterpret_cast<const short8*>(qrow + 48 * HD + 32);

    short8 ones;
#pragma unroll
    for (int i = 0; i < 8; ++i) ones[i] = (short)0x3F80;  // bf16 1.0

    f32x4 O[16];
#pragma unroll
    for (int i = 0; i < 16; ++i) O[i] = (f32x4){0.f, 0.f, 0.f, 0.f};
    f32x4 l4A = (f32x4){0.f, 0.f, 0.f, 0.f};
    f32x4 l4B = (f32x4){0.f, 0.f, 0.f, 0.f};
    f32x4 l4C = (f32x4){0.f, 0.f, 0.f, 0.f};
    f32x4 l4D = (f32x4){0.f, 0.f, 0.f, 0.f};
    const int qgA = q0 + li;
    const int qgB = q0 + 16 + li;
    const int qgC = q0 + 32 + li;
    const int qgD = q0 + 48 + li;
    const f32x4 z4 = (f32x4){0.f, 0.f, 0.f, 0.f};

    // fragment-major tile bases: + l*8 makes every load lane-linear (16B/lane)
    const u16* kbase = kw  + (long)(b * 64) * 4096 + l * 8;
    const u16* vbase = vpw + (long)(b * 64) * 4096 + l * 8;
    const int tLast = ntile - 1;

    short8 ka[8];
    short8 vf[8];
    auto kload = [&](int i) {                     // clamped prefetch, tile idx
        const int tt = (i > tLast) ? tLast : i;
        const u16* kp = kbase + (long)(ktBeg + tt) * 4096;
#pragma unroll
        for (int m = 0; m < 8; ++m)
            ka[m] = *reinterpret_cast<const short8*>(kp + m * 512);
    };
    auto vfload = [&](int i) {
        const u16* vr = vbase + (long)(ktBeg + i) * 4096;
#pragma unroll
        for (int m = 0; m < 8; ++m)
            vf[m] = *reinterpret_cast<const short8*>(vr + m * 512);
    };
    auto sphase = [&](int i) {            // S^T + softmax -> Ps[w][qs], 4 subtiles
        const int k0 = (ktBeg + i) * 64;
        const u32 mb0 = maskbits[b * 128 + (k0 >> 5)];
        const u32 mb1 = maskbits[b * 128 + (k0 >> 5) + 1];
#pragma unroll
        for (int sub = 0; sub < 4; ++sub) {
            const u32 word = (sub & 2) ? mb1 : mb0;
            const int klb = k0 + sub * 16 + g4;
            const int sh  = (sub & 1) * 16 + g4;
            // subtile A
            {
                f32x4 a = __builtin_amdgcn_mfma_f32_16x16x32_bf16(ka[2*sub],   qf0, z4, 0, 0, 0);
                a       = __builtin_amdgcn_mfma_f32_16x16x32_bf16(ka[2*sub+1], qf1, a,  0, 0, 0);
                float p[4];
#pragma unroll
                for (int r = 0; r < 4; ++r) {
                    const bool keep = ((klb + r) <= qgA) && (((word >> (sh + r)) & 1u) != 0u);
                    p[r] = ex2(fmaf(a[r], SSCALE, keep ? CSHIFT : NEGBIG));
                }
                *reinterpret_cast<uint2*>(&Ps[w][0][li][sub * 16 + g4]) =
                    make_uint2(pkbf(p[0], p[1]), pkbf(p[2], p[3]));
            }
            // subtile B
            {
                f32x4 a = __builtin_amdgcn_mfma_f32_16x16x32_bf16(ka[2*sub],   qf2, z4, 0, 0, 0);
                a       = __builtin_amdgcn_mfma_f32_16x16x32_bf16(ka[2*sub+1], qf3, a,  0, 0, 0);
                float p[4];
#pragma unroll
                for (int r = 0; r < 4; ++r) {
                    const bool keep = ((klb + r) <= qgB) && (((word >> (sh + r)) & 1u) != 0u);
                    p[r] = ex2(fmaf(a[r], SSCALE, keep ? CSHIFT : NEGBIG));
                }
                *reinterpret_cast<uint2*>(&Ps[w][1][li][sub * 16 + g4]) =
                    make_uint2(pkbf(p[0], p[1]), pkbf(p[2], p[3]));
            }
            // subtile C
            {
                f32x4 a = __builtin_amdgcn_mfma_f32_16x16x32_bf16(ka[2*sub],   qf4, z4, 0, 0, 0);
                a       = __builtin_amdgcn_mfma_f32_16x16x32_bf16(ka[2*sub+1], qf5, a,  0, 0, 0);
                float p[4];
#pragma unroll
                for (int r = 0; r < 4; ++r) {
                    const bool keep = ((klb + r) <= qgC) && (((word >> (sh + r)) & 1u) != 0u);
                    p[r] = ex2(fmaf(a[r], SSCALE, keep ? CSHIFT : NEGBIG));
                }
                *reinterpret_cast<uint2*>(&Ps[w][2][li][sub * 16 + g4]) =
                    make_uint2(pkbf(p[0], p[1]), pkbf(p[2], p[3]));
            }
            // subtile D
            {
                f32x4 a = __builtin_amdgcn_mfma_f32_16x16x32_bf16(ka[2*sub],   qf6, z4, 0, 0, 0);
                a       = __builtin_amdgcn_mfma_f32_16x16x32_bf16(ka[2*sub+1], qf7, a,  0, 0, 0);
                float p[4];
#pragma unroll
                for (int r = 0; r < 4; ++r) {
                    const bool keep = ((klb + r) <= qgD) && (((word >> (sh + r)) & 1u) != 0u);
                    p[r] = ex2(fmaf(a[r], SSCALE, keep ? CSHIFT : NEGBIG));
                }
                *reinterpret_cast<uint2*>(&Ps[w][3][li][sub * 16 + g4]) =
                    make_uint2(pkbf(p[0], p[1]), pkbf(p[2], p[3]));
            }
        }
    };

    kload(0);
    sphase(0);
    kload(1);
    for (int i = 0; i < ntile; ++i) {
        __builtin_amdgcn_s_barrier();   // convoy: keep 4 waves on same tile
        vfload(i);
        short8 A1A = *reinterpret_cast<const short8*>(&Ps[w][0][li][g * 8]);
        short8 A2A = *reinterpret_cast<const short8*>(&Ps[w][0][li][32 + g * 8]);
        short8 A1B = *reinterpret_cast<const short8*>(&Ps[w][1][li][g * 8]);
        short8 A2B = *reinterpret_cast<const short8*>(&Ps[w][1][li][32 + g * 8]);
        short8 A1C = *reinterpret_cast<const short8*>(&Ps[w][2][li][g * 8]);
        short8 A2C = *reinterpret_cast<const short8*>(&Ps[w][2][li][32 + g * 8]);
        short8 A1D = *reinterpret_cast<const short8*>(&Ps[w][3][li][g * 8]);
        short8 A2D = *reinterpret_cast<const short8*>(&Ps[w][3][li][32 + g * 8]);
        if (i + 1 < ntile) {
            sphase(i + 1);               // overwrites Ps AFTER the reg-reads above
            kload(i + 2);                // refill single K buffer (clamped)
        }
        f32x4 lt;
        lt = __builtin_amdgcn_mfma_f32_16x16x32_bf16(A1A, ones, z4, 0, 0, 0);
        lt = __builtin_amdgcn_mfma_f32_16x16x32_bf16(A2A, ones, lt, 0, 0, 0);
#pragma unroll
        for (int r = 0; r < 4; ++r) l4A[r] += lt[r];
        lt = __builtin_amdgcn_mfma_f32_16x16x32_bf16(A1B, ones, z4, 0, 0, 0);
        lt = __builtin_amdgcn_mfma_f32_16x16x32_bf16(A2B, ones, lt, 0, 0, 0);
#pragma unroll
        for (int r = 0; r < 4; ++r) l4B[r] += lt[r];
        lt = __builtin_amdgcn_mfma_f32_16x16x32_bf16(A1C, ones, z4, 0, 0, 0);
        lt = __builtin_amdgcn_mfma_f32_16x16x32_bf16(A2C, ones, lt, 0, 0, 0);
#pragma unroll
        for (int r = 0; r < 4; ++r) l4C[r] += lt[r];
        lt = __builtin_amdgcn_mfma_f32_16x16x32_bf16(A1D, ones, z4, 0, 0, 0);
        lt = __builtin_amdgcn_mfma_f32_16x16x32_bf16(A2D, ones, lt, 0, 0, 0);
#pragma unroll
        for (int r = 0; r < 4; ++r) l4D[r] += lt[r];
#pragma unroll
        for (int ds = 0; ds < 4; ++ds) {
            O[ds]      = __builtin_amdgcn_mfma_f32_16x16x32_bf16(A1A, vf[2*ds],   O[ds],      0, 0, 0);
            O[ds]      = __builtin_amdgcn_mfma_f32_16x16x32_bf16(A2A, vf[2*ds+1], O[ds],      0, 0, 0);
            O[4 + ds]  = __builtin_amdgcn_mfma_f32_16x16x32_bf16(A1B, vf[2*ds],   O[4 + ds],  0, 0, 0);
            O[4 + ds]  = __builtin_amdgcn_mfma_f32_16x16x32_bf16(A2B, vf[2*ds+1], O[4 + ds],  0, 0, 0);
            O[8 + ds]  = __builtin_amdgcn_mfma_f32_16x16x32_bf16(A1C, vf[2*ds],   O[8 + ds],  0, 0, 0);
            O[8 + ds]  = __builtin_amdgcn_mfma_f32_16x16x32_bf16(A2C, vf[2*ds+1], O[8 + ds],  0, 0, 0);
            O[12 + ds] = __builtin_amdgcn_mfma_f32_16x16x32_bf16(A1D, vf[2*ds],   O[12 + ds], 0, 0, 0);
            O[12 + ds] = __builtin_amdgcn_mfma_f32_16x16x32_bf16(A2D, vf[2*ds+1], O[12 + ds], 0, 0, 0);
        }
    }

    // ---- per-wave epilogue: two 32-row passes through this wave's Ps region ----
    {
        float* Of = reinterpret_cast<float*>(&Ps[w][0][0][0]);
        float* Lf = Of + 2112;
        const int r32 = l >> 1;          // 0..31: output row within pass
        const int h   = l & 1;           // column half (32 cols)
#pragma unroll
        for (int p = 0; p < 2; ++p) {
#pragma unroll
            for (int tile = 0; tile < 2; ++tile)
#pragma unroll
                for (int ds = 0; ds < 4; ++ds)
#pragma unroll
                    for (int r = 0; r < 4; ++r)
                        Of[(tile * 16 + g4 + r) * 66 + ds * 16 + li] =
                            O[(p * 2 + tile) * 4 + ds][r];
            if (li == 0) {
#pragma unroll
                for (int r = 0; r < 4; ++r) {
                    Lf[g4 + r]      = p ? l4C[r] : l4A[r];
                    Lf[16 + g4 + r] = p ? l4D[r] : l4B[r];
                }
            }
            float v[32];
#pragma unroll
            for (int j = 0; j < 8; ++j) {
                float4 f = *reinterpret_cast<const float4*>(&Of[r32 * 66 + h * 32 + j * 4]);
                v[4*j] = f.x; v[4*j+1] = f.y; v[4*j+2] = f.z; v[4*j+3] = f.w;
            }
            if (single) {
                const float L = Lf[r32];
                const float rl = (L > 0.f) ? 1.f / L : 0.f;
#pragma unroll
                for (int j = 0; j < 32; ++j) v[j] *= rl;
                const long row = (long)(b * SEQ + q0 + p * 32 + r32);
                if (flag) {
                    u16* dst = (u16*)out + row * HD + h * 32;
#pragma unroll
                    for (int jj = 0; jj < 4; ++jj) {
                        uint4 st = make_uint4(pkbf(v[8*jj],   v[8*jj+1]), pkbf(v[8*jj+2], v[8*jj+3]),
                                              pkbf(v[8*jj+4], v[8*jj+5]), pkbf(v[8*jj+6], v[8*jj+7]));
                        *reinterpret_cast<uint4*>(dst + jj * 8) = st;
                    }
                } else {
                    float* dst = (float*)out + row * HD + h * 32;
#pragma unroll
                    for (int jj = 0; jj < 8; ++jj)
                        *reinterpret_cast<float4*>(dst + jj * 4) =
                            make_float4(v[4*jj], v[4*jj+1], v[4*jj+2], v[4*jj+3]);
                }
            } else {
                const int slotIdx = ((b * 72 + chunk_off(qt256) + c) * 8 + w * 2 + p);
                char* slot = part + (long)slotIdx * PSLOTB;
                u16* dst = (u16*)slot + r32 * 64 + h * 32;
#pragma unroll
                for (int jj = 0; jj < 4; ++jj) {
                    uint4 st = make_uint4(pkbf(v[8*jj],   v[8*jj+1]), pkbf(v[8*jj+2], v[8*jj+3]),
                                          pkbf(v[8*jj+4], v[8*jj+5]), pkbf(v[8*jj+6], v[8*jj+7]));
                    *reinterpret_cast<uint4*>(dst + jj * 8) = st;
                }
                if (l < 32)
                    *reinterpret_cast<float*>(slot + 4096 + l * 4) = Lf[l];
            }
        }
    }
}

// ---------------- merge split-K partials (qt256 >= 2): plain sum ----------
__global__ __launch_bounds__(256) void merge_kernel(
    const u32* __restrict__ xs, const char* __restrict__ part,
    void* __restrict__ out)
{
    const int flag = sniff_bf16(xs);
    const int bid = blockIdx.x;         // 448
    const int b = bid & 3;
    const int u = bid >> 2;             // 0..111
    const int qt256 = 2 + u / 8;        // 2..15
    const int v8 = u % 8;
    const int w = v8 >> 1;              // wave 0..3
    const int p = v8 & 1;               // half-pass 0..1
    const int nc = (qt256 >> 1) + 1;    // 2..8 chunks
    const int t  = threadIdx.x;
    const int qq = t >> 3;              // 0..31
    const int dd = (t & 7) * 8;         // 0..56
    const char* s0 = part +
        ((long)((b * 72 + chunk_off(qt256)) * 8 + w * 2 + p)) * PSLOTB;
    float L = 0.f;
    float a8[8];
#pragma unroll
    for (int j = 0; j < 8; ++j) a8[j] = 0.f;
    for (int c = 0; c < nc; ++c) {
        const char* sc = s0 + (long)c * 8 * PSLOTB;   // c-stride = 8 slots
        L += *reinterpret_cast<const float*>(sc + 4096 + qq * 4);
        ushort4 x0 = *reinterpret_cast<const ushort4*>((const u16*)sc + qq * 64 + dd);
        ushort4 x1 = *reinterpret_cast<const ushort4*>((const u16*)sc + qq * 64 + dd + 4);
        a8[0] += bfbits2f(x0.x); a8[1] += bfbits2f(x0.y);
        a8[2] += bfbits2f(x0.z); a8[3] += bfbits2f(x0.w);
        a8[4] += bfbits2f(x1.x); a8[5] += bfbits2f(x1.y);
        a8[6] += bfbits2f(x1.z); a8[7] += bfbits2f(x1.w);
    }
    const float rl = (L > 0.f) ? 1.f / L : 0.f;
#pragma unroll
    for (int j = 0; j < 8; ++j) a8[j] *= rl;
    const long row = (long)(b * SEQ + qt256 * 256 + w * 64 + p * 32 + qq);
    if (flag) {
        uint4 st = make_uint4(pkbf(a8[0], a8[1]), pkbf(a8[2], a8[3]),
                              pkbf(a8[4], a8[5]), pkbf(a8[6], a8[7]));
        *reinterpret_cast<uint4*>((u16*)out + row * HD + dd) = st;
    } else {
        *reinterpret_cast<float4*>((float*)out + row * HD + dd) =
            make_float4(a8[0], a8[1], a8[2], a8[3]);
        *reinterpret_cast<float4*>((float*)out + row * HD + dd + 4) =
            make_float4(a8[4], a8[5], a8[6], a8[7]);
    }
}

extern "C" void kernel_launch(void* const* d_in, const int* in_sizes, int n_in,
                              void* d_out, int out_size, void* d_ws, size_t ws_size,
                              hipStream_t stream) {
    const void* x   = d_in[0];
    const int* mask = (const int*)d_in[1];
    const void* wq  = d_in[2];
    const void* wk  = d_in[3];
    const void* wv  = d_in[4];
    const u32* xs   = (const u32*)x;

    u16* q    = (u16*)d_ws;                          // 2 MB
    u16* k    = q  + (long)NROW * HD;                // 2 MB (fragment-major tiles)
    u16* vp   = k  + (long)NROW * HD;                // 2 MB (fragment-major tiles)
    u32* mb   = (u32*)(vp + (long)NROW * HD);        // 2 KB
    char* part = (char*)(mb + 512);                  // 2304 slots = 9.73 MB
    u16* wb   = (u16*)(part + (long)NSLOT * PSLOTB); // 288 KB bf16 W

    wconv_kernel<<<72, 256, 0, stream>>>(xs, wq, wk, wv, wb);
    qkv_kernel  <<<258, 512, 0, stream>>>(x, wb, mask, q, k, vp, mb);
    attn_kernel <<<288, 256, 0, stream>>>(xs, q, k, vp, mb, part, d_out);
    merge_kernel<<<448, 256, 0, stream>>>(xs, part, d_out);
}